// Round 1
// 629.242 us; speedup vs baseline: 2.0086x; 2.0086x over previous
//
#include <hip/hip_runtime.h>
#include <hip/hip_bf16.h>
#include <math.h>

#define HEADS 8
#define DH 32
#define BATCH 8
#define CDIM 512
#define NSEQ 8192
#define HID 256
#define O3 768
#define LNEPS 1e-5f
#define QSCALE 0.1767766952966369f  // 32^-0.5

typedef __bf16 bf16x8 __attribute__((ext_vector_type(8)));
typedef float f32x4 __attribute__((ext_vector_type(4)));
typedef unsigned short u16;
typedef u16 u16x4 __attribute__((ext_vector_type(4)));
typedef u16 u16x8 __attribute__((ext_vector_type(8)));

// dual-dtype element load: mode==1 -> fp32 buffer, mode==0 -> bf16 buffer
__device__ __forceinline__ float ldx(const void* p, size_t i, bool f32) {
  if (f32) {
    float v = ((const float*)p)[i];
    return __builtin_isfinite(v) ? v : 0.f;
  }
  return __bfloat162float(((const __hip_bfloat16*)p)[i]);
}

__device__ __forceinline__ u16 b16(float v) {
  union { __hip_bfloat16 h; u16 u; } cv;
  cv.h = __float2bfloat16(v);
  return cv.u;
}

__device__ __forceinline__ float fb16(u16 u) {
  return __uint_as_float((unsigned)u << 16);
}

// stage 8 contiguous elements into LDS as bf16 (legacy path)
__device__ __forceinline__ void stage8(__hip_bfloat16* dst, const void* src, size_t idx, bool f32) {
  if (f32) {
    const float* s = (const float*)src + idx;
#pragma unroll
    for (int t = 0; t < 8; ++t) {
      float v = s[t];
      if (!__builtin_isfinite(v)) v = 0.f;
      dst[t] = __float2bfloat16(v);
    }
  } else {
    *(int4*)dst = *(const int4*)((const __hip_bfloat16*)src + idx);
  }
}

// dual-dtype store with finite scrub
__device__ __forceinline__ void stx(void* p, size_t i, bool f32, float v) {
  if (!__builtin_isfinite(v)) v = 0.f;
  if (f32) ((float*)p)[i] = v;
  else ((__hip_bfloat16*)p)[i] = __float2bfloat16(v);
}

// ---------------- kernel 0: dtype detector ----------------
__global__ __launch_bounds__(256) void detect_kernel(const void* __restrict__ x, int* __restrict__ mode) {
  __shared__ int cnt;
  if (threadIdx.x == 0) cnt = 0;
  __syncthreads();
  const __hip_bfloat16* p = (const __hip_bfloat16*)x;
  int c = 0;
  for (int i = threadIdx.x; i < 4096; i += 256) {
    float v = __bfloat162float(p[i]);
    if (!(v > -1.0e3f && v < 1.0e3f)) c++;
  }
  atomicAdd(&cnt, c);
  __syncthreads();
  if (threadIdx.x == 0) mode[0] = (cnt > 64) ? 1 : 0;
}

// ---------------- NEW kernel: LN stats, float4-vectorized ----------------
// grid (NSEQ/128, BATCH); thread owns 4 n-columns, 8 c-partitions of 64.
__global__ __launch_bounds__(256) void ln_stats4_kernel(
    const void* __restrict__ x, const int* __restrict__ mode,
    float* __restrict__ mean, float* __restrict__ rstd) {
  const bool f32 = mode[0] != 0;
  const int b = blockIdx.y;
  const int n0 = blockIdx.x * 128;
  const int t = threadIdx.x;
  const int m = t & 31, cp = t >> 5;
  const int n4 = m * 4;
  const size_t base = (size_t)b * CDIM * NSEQ + n0 + n4;
  f32x4 s = {0.f, 0.f, 0.f, 0.f}, q = {0.f, 0.f, 0.f, 0.f};
  for (int c = cp * 64; c < cp * 64 + 64; ++c) {
    f32x4 v;
    if (f32) {
      v = *(const f32x4*)((const float*)x + base + (size_t)c * NSEQ);
#pragma unroll
      for (int j = 0; j < 4; ++j) if (!__builtin_isfinite(v[j])) v[j] = 0.f;
    } else {
      u16x4 h = *(const u16x4*)((const __hip_bfloat16*)x + base + (size_t)c * NSEQ);
#pragma unroll
      for (int j = 0; j < 4; ++j) v[j] = fb16(h[j]);
    }
    s += v;
    q += v * v;
  }
  __shared__ f32x4 sbS[8][32], sbQ[8][32];
  sbS[cp][m] = s; sbQ[cp][m] = q;
  __syncthreads();
  if (t < 32) {
    f32x4 S = sbS[0][t], Q = sbQ[0][t];
#pragma unroll
    for (int k = 1; k < 8; ++k) { S += sbS[k][t]; Q += sbQ[k][t]; }
    f32x4 M = S * (1.f / CDIM);
    f32x4 V = Q * (1.f / CDIM) - M * M;
#pragma unroll
    for (int j = 0; j < 4; ++j) {
      mean[b * NSEQ + n0 + t * 4 + j] = M[j];
      rstd[b * NSEQ + n0 + t * 4 + j] = rsqrtf(fmaxf(V[j], 0.f) + LNEPS);
    }
  }
}

// ---------------- NEW kernel: wqkv -> bf16 once ----------------
__global__ __launch_bounds__(256) void wconv_kernel(
    const void* __restrict__ wqkv, const int* __restrict__ mode,
    __hip_bfloat16* __restrict__ wb) {
  const bool f32 = mode[0] != 0;
  const size_t i = ((size_t)blockIdx.x * 256 + threadIdx.x) * 8;
  if (f32) {
    f32x4 a = *(const f32x4*)((const float*)wqkv + i);
    f32x4 c = *(const f32x4*)((const float*)wqkv + i + 4);
    u16x8 o;
#pragma unroll
    for (int j = 0; j < 4; ++j) {
      float va = __builtin_isfinite(a[j]) ? a[j] : 0.f;
      float vc = __builtin_isfinite(c[j]) ? c[j] : 0.f;
      o[j] = b16(va);
      o[4 + j] = b16(vc);
    }
    *(u16x8*)&wb[i] = o;
  } else {
    *(int4*)&wb[i] = *(const int4*)((const __hip_bfloat16*)wqkv + i);
  }
}

// ---------------- NEW kernel: xnormT[b][n][c] bf16 via LDS transpose ----------------
// grid (NSEQ/128, CDIM/128, BATCH). Phase1: coalesced reads along n, LN in-register,
// bf16 into LDS [c][n]. Phase2: column gather -> int4 row-major stores along c.
__global__ __launch_bounds__(256) void xnormt_kernel(
    const void* __restrict__ x, const void* __restrict__ g, const void* __restrict__ bln,
    const int* __restrict__ mode, const float* __restrict__ mean, const float* __restrict__ rstd,
    __hip_bfloat16* __restrict__ xnt) {
  const bool f32 = mode[0] != 0;
  const int b = blockIdx.z;
  const int c0 = blockIdx.y * 128;
  const int n0 = blockIdx.x * 128;
  __shared__ u16 tile[128 * 132];  // [c][n] pad 132: phase2 4-way worst case
  const int t = threadIdx.x;
  const int m = t & 31, rb = t >> 5;
  const int n4 = m * 4;
  const f32x4 mn = *(const f32x4*)&mean[b * NSEQ + n0 + n4];
  const f32x4 rs = *(const f32x4*)&rstd[b * NSEQ + n0 + n4];
#pragma unroll
  for (int it = 0; it < 16; ++it) {
    const int r = it * 8 + rb;
    const float gv = ldx(g, c0 + r, f32);
    const float bv = ldx(bln, c0 + r, f32);
    const size_t src = ((size_t)b * CDIM + c0 + r) * NSEQ + n0 + n4;
    f32x4 v;
    if (f32) {
      v = *(const f32x4*)((const float*)x + src);
#pragma unroll
      for (int j = 0; j < 4; ++j) if (!__builtin_isfinite(v[j])) v[j] = 0.f;
    } else {
      u16x4 h = *(const u16x4*)((const __hip_bfloat16*)x + src);
#pragma unroll
      for (int j = 0; j < 4; ++j) v[j] = fb16(h[j]);
    }
    u16x4 o;
#pragma unroll
    for (int j = 0; j < 4; ++j) o[j] = b16((v[j] - mn[j]) * rs[j] * gv + bv);
    *(u16x4*)&tile[r * 132 + n4] = o;
  }
  __syncthreads();
  const int n = t >> 1, ch = t & 1;
  __hip_bfloat16* dst = xnt + ((size_t)b * NSEQ + n0 + n) * CDIM + c0 + ch * 64;
#pragma unroll
  for (int i8 = 0; i8 < 8; ++i8) {
    u16x8 o;
#pragma unroll
    for (int k = 0; k < 8; ++k) o[k] = tile[(ch * 64 + i8 * 8 + k) * 132 + n];
    *(u16x8*)(dst + i8 * 8) = o;
  }
}

// ---------------- legacy kernel 1: LayerNorm stats ----------------
__global__ __launch_bounds__(256) void ln_stats_kernel(
    const void* __restrict__ x, const int* __restrict__ mode,
    float* __restrict__ mean, float* __restrict__ rstd) {
  const bool f32 = mode[0] != 0;
  int b = blockIdx.y;
  int nl = threadIdx.x & 63;
  int cp = threadIdx.x >> 6;
  int n = blockIdx.x * 64 + nl;
  size_t base = (size_t)b * CDIM * NSEQ + n;
  float s = 0.f, ss = 0.f;
  for (int c = cp * 128; c < cp * 128 + 128; ++c) {
    float v = ldx(x, base + (size_t)c * NSEQ, f32);
    s += v; ss += v * v;
  }
  __shared__ float sb[4][64], sb2[4][64];
  sb[cp][nl] = s; sb2[cp][nl] = ss;
  __syncthreads();
  if (cp == 0) {
    s = sb[0][nl] + sb[1][nl] + sb[2][nl] + sb[3][nl];
    ss = sb2[0][nl] + sb2[1][nl] + sb2[2][nl] + sb2[3][nl];
    float m = s * (1.f / CDIM);
    float var = ss * (1.f / CDIM) - m * m;
    mean[b * NSEQ + n] = m;
    rstd[b * NSEQ + n] = rsqrtf(fmaxf(var, 0.f) + LNEPS);
  }
}

// ---------------- NEW kernel: K/V GEMM + exp + context (vector-staged) ----------------
__global__ __launch_bounds__(256) void kv_gemm2_kernel(
    const __hip_bfloat16* __restrict__ wb, const __hip_bfloat16* __restrict__ xnt,
    float* __restrict__ ctxb, float* __restrict__ sumexp) {
  const int b = blockIdx.z;
  const int p = blockIdx.y;
  const int n0 = blockIdx.x * 128;
  __shared__ __align__(16) char smem[128 * 136 * 2];  // union: As+Bs (20.5KB) / Ct (34KB)
  __hip_bfloat16* As = (__hip_bfloat16*)smem;
  __hip_bfloat16* Bs = As + 128 * 40;
  __hip_bfloat16* Ct = (__hip_bfloat16*)smem;
  const int tid = threadIdx.x;
  const int lane = tid & 63;
  const int wv = tid >> 6;
  const int wm = wv >> 1, wn = wv & 1;
  const int quad = lane >> 4, l = lane & 15;
  f32x4 acc[4][4] = {};
  const __hip_bfloat16* xb = xnt + (size_t)b * NSEQ * CDIM;
  for (int k0 = 0; k0 < CDIM; k0 += 32) {
#pragma unroll
    for (int i = 0; i < 2; ++i) {
      int gid = tid + i * 256;
      int row = gid >> 2, c8 = (gid & 3) * 8;
      int srow = (row < 64) ? (256 + p * 64 + row) : (512 + p * 64 + row - 64);
      *(int4*)&As[row * 40 + c8] = *(const int4*)&wb[(size_t)srow * CDIM + k0 + c8];
      *(int4*)&Bs[row * 40 + c8] = *(const int4*)&xb[(size_t)(n0 + row) * CDIM + k0 + c8];
    }
    __syncthreads();
    bf16x8 af[4], bfr[4];
#pragma unroll
    for (int i = 0; i < 4; ++i)
      af[i] = *(const bf16x8*)&As[(wm * 64 + i * 16 + l) * 40 + quad * 8];
#pragma unroll
    for (int j = 0; j < 4; ++j)
      bfr[j] = *(const bf16x8*)&Bs[(wn * 64 + j * 16 + l) * 40 + quad * 8];
#pragma unroll
    for (int i = 0; i < 4; ++i)
#pragma unroll
      for (int j = 0; j < 4; ++j)
        acc[i][j] = __builtin_amdgcn_mfma_f32_16x16x32_bf16(af[i], bfr[j], acc[i][j], 0, 0, 0);
    __syncthreads();
  }
  // epilogue: exp on K half (rows 0..63), clamp V half; write C tile to LDS (aliases As/Bs - safe post-barrier)
#pragma unroll
  for (int i = 0; i < 4; ++i) {
    int row = wm * 64 + i * 16 + quad * 4;
#pragma unroll
    for (int j = 0; j < 4; ++j) {
      int col = wn * 64 + j * 16 + l;
#pragma unroll
      for (int r = 0; r < 4; ++r) {
        float v = acc[i][j][r];
        if (wm == 0) v = expf(fminf(v, 20.f));
        else         v = fminf(fmaxf(v, -1.0e4f), 1.0e4f);
        Ct[(row + r) * 136 + col] = __float2bfloat16(v);
      }
    }
  }
  __syncthreads();
  const int mi = wm, ni = wn;
#pragma unroll
  for (int hh = 0; hh < 2; ++hh) {
    f32x4 ca = {};
#pragma unroll
    for (int ks = 0; ks < 4; ++ks) {
      bf16x8 ea = *(const bf16x8*)&Ct[(hh * 32 + mi * 16 + l) * 136 + ks * 32 + quad * 8];
      bf16x8 vb = *(const bf16x8*)&Ct[(64 + hh * 32 + ni * 16 + l) * 136 + ks * 32 + quad * 8];
      ca = __builtin_amdgcn_mfma_f32_16x16x32_bf16(ea, vb, ca, 0, 0, 0);
    }
    int h = p * 2 + hh;
    float* cp = ctxb + (size_t)(b * HEADS + h) * DH * DH;
#pragma unroll
    for (int r = 0; r < 4; ++r)
      atomicAdd(&cp[(mi * 16 + quad * 4 + r) * DH + ni * 16 + l], ca[r]);
  }
  if (tid < 64) {
    int hh = tid >> 5, d = tid & 31;
    float s = 0.f;
#pragma unroll 16
    for (int c = 0; c < 128; ++c) s += __bfloat162float(Ct[tid * 136 + c]);
    atomicAdd(&sumexp[(b * HEADS + p * 2 + hh) * DH + d], s);
  }
}

// ---------------- legacy kernel 2: fused K/V GEMM + exp + context ----------------
__global__ __launch_bounds__(256) void kvctx_kernel(
    const void* __restrict__ x, const void* __restrict__ g,
    const void* __restrict__ bln, const void* __restrict__ wqkv,
    const int* __restrict__ mode,
    const float* __restrict__ mean, const float* __restrict__ rstd,
    float* __restrict__ ctxb, float* __restrict__ sumexp) {
  const bool f32 = mode[0] != 0;
  const int b = blockIdx.z;
  const int p = blockIdx.y;
  const int n0 = blockIdx.x * 128;
  __shared__ __align__(16) __hip_bfloat16 As[128 * 32];
  __shared__ __align__(16) __hip_bfloat16 Bs[128 * 40];
  __shared__ __align__(16) __hip_bfloat16 Ct[128 * 136];
  const int tid = threadIdx.x;
  const int lane = tid & 63;
  const int wv = tid >> 6;
  const int wm = wv >> 1, wn = wv & 1;
  const int quad = lane >> 4, l = lane & 15;
  f32x4 acc[4][4] = {};
  const int nn = tid & 127;
  const int cb = tid >> 7;
  const float mn = mean[b * NSEQ + n0 + nn];
  const float rs = rstd[b * NSEQ + n0 + nn];
  const size_t xbase = (size_t)b * CDIM * NSEQ + n0 + nn;
  for (int k0 = 0; k0 < CDIM; k0 += 32) {
#pragma unroll
    for (int r = 0; r < 2; ++r) {
      int idx = (r * 256 + tid) * 8;
      int row = idx >> 5, col = idx & 31;
      int srow = (row < 64) ? (256 + p * 64 + row) : (512 + p * 64 + row - 64);
      stage8(&As[idx], wqkv, (size_t)srow * CDIM + k0 + col, f32);
    }
#pragma unroll
    for (int r = 0; r < 16; ++r) {
      int c = r * 2 + cb;
      float xv = ldx(x, xbase + (size_t)(k0 + c) * NSEQ, f32);
      float xn = (xv - mn) * rs;
      xn = xn * ldx(g, k0 + c, f32) + ldx(bln, k0 + c, f32);
      Bs[nn * 40 + c] = __float2bfloat16(xn);
    }
    __syncthreads();
    bf16x8 af[4], bfr[4];
#pragma unroll
    for (int i = 0; i < 4; ++i)
      af[i] = *(const bf16x8*)&As[(wm * 64 + i * 16 + l) * 32 + quad * 8];
#pragma unroll
    for (int j = 0; j < 4; ++j)
      bfr[j] = *(const bf16x8*)&Bs[(wn * 64 + j * 16 + l) * 40 + quad * 8];
#pragma unroll
    for (int i = 0; i < 4; ++i)
#pragma unroll
      for (int j = 0; j < 4; ++j)
        acc[i][j] = __builtin_amdgcn_mfma_f32_16x16x32_bf16(af[i], bfr[j], acc[i][j], 0, 0, 0);
    __syncthreads();
  }
#pragma unroll
  for (int i = 0; i < 4; ++i) {
    int row = wm * 64 + i * 16 + quad * 4;
#pragma unroll
    for (int j = 0; j < 4; ++j) {
      int col = wn * 64 + j * 16 + l;
#pragma unroll
      for (int r = 0; r < 4; ++r) {
        float v = acc[i][j][r];
        if (wm == 0) v = expf(fminf(v, 20.f));
        else         v = fminf(fmaxf(v, -1.0e4f), 1.0e4f);
        Ct[(row + r) * 136 + col] = __float2bfloat16(v);
      }
    }
  }
  __syncthreads();
  const int mi = wm, ni = wn;
#pragma unroll
  for (int hh = 0; hh < 2; ++hh) {
    f32x4 ca = {};
#pragma unroll
    for (int ks = 0; ks < 4; ++ks) {
      bf16x8 ea = *(const bf16x8*)&Ct[(hh * 32 + mi * 16 + l) * 136 + ks * 32 + quad * 8];
      bf16x8 vb = *(const bf16x8*)&Ct[(64 + hh * 32 + ni * 16 + l) * 136 + ks * 32 + quad * 8];
      ca = __builtin_amdgcn_mfma_f32_16x16x32_bf16(ea, vb, ca, 0, 0, 0);
    }
    int h = p * 2 + hh;
    float* cp = ctxb + (size_t)(b * HEADS + h) * DH * DH;
#pragma unroll
    for (int r = 0; r < 4; ++r)
      atomicAdd(&cp[(mi * 16 + quad * 4 + r) * DH + ni * 16 + l], ca[r]);
  }
  if (tid < 64) {
    int hh = tid >> 5, d = tid & 31;
    float s = 0.f;
#pragma unroll 16
    for (int c = 0; c < 128; ++c) s += __bfloat162float(Ct[tid * 136 + c]);
    atomicAdd(&sumexp[(b * HEADS + p * 2 + hh) * DH + d], s);
  }
}

// ---------------- kernel 3: W2 build (clamped) ----------------
__global__ __launch_bounds__(256) void w2_build_kernel(
    const void* __restrict__ wout, const int* __restrict__ mode,
    const float* __restrict__ ctxb, const float* __restrict__ sumexp,
    __hip_bfloat16* __restrict__ w2) {
  const bool f32 = mode[0] != 0;
  const int o = blockIdx.x;
  const int b = blockIdx.y;
  const int hd = threadIdx.x;
  const int h = hd >> 5, d = hd & 31;
  const float* cp = ctxb + ((size_t)(b * HEADS + h) * DH + d) * DH;
  float a = 0.f;
#pragma unroll
  for (int e = 0; e < DH; ++e) a += ldx(wout, (size_t)o * HID + h * DH + e, f32) * cp[e];
  float se = fmaxf(sumexp[(b * HEADS + h) * DH + d], 1e-30f);
  float v = a * QSCALE / se;
  v = fminf(fmaxf(v, -1.0e3f), 1.0e3f);
  w2[((size_t)b * CDIM + o) * HID + hd] = __float2bfloat16(v);
}

// ---------------- NEW kernel: W3[b] = W2[b] (512x256) * Wq (256x512), bf16 sources ----------------
__global__ __launch_bounds__(256) void w3_gemm2_kernel(
    const __hip_bfloat16* __restrict__ w2, const __hip_bfloat16* __restrict__ wb,
    __hip_bfloat16* __restrict__ w3) {
  const int b = blockIdx.z;
  const int m0 = blockIdx.y * 128;
  const int n0 = blockIdx.x * 128;
  __shared__ __align__(16) __hip_bfloat16 As[128 * 40];
  __shared__ __align__(16) __hip_bfloat16 Bs[128 * 40];
  const int tid = threadIdx.x;
  const int lane = tid & 63;
  const int wv = tid >> 6;
  const int wm = wv >> 1, wn = wv & 1;
  const int quad = lane >> 4, l = lane & 15;
  f32x4 acc[4][4] = {};
  const int nn = tid & 127;
  const int cb = tid >> 7;
  const __hip_bfloat16* wa = w2 + (size_t)b * CDIM * HID;
  for (int k0 = 0; k0 < HID; k0 += 32) {
#pragma unroll
    for (int i = 0; i < 2; ++i) {
      int gid = tid + i * 256;
      int row = gid >> 2, c8 = (gid & 3) * 8;
      *(int4*)&As[row * 40 + c8] = *(const int4*)&wa[(size_t)(m0 + row) * HID + k0 + c8];
    }
#pragma unroll
    for (int r = 0; r < 16; ++r) {
      int hdl = r * 2 + cb;
      Bs[nn * 40 + hdl] = wb[(size_t)(k0 + hdl) * CDIM + n0 + nn];
    }
    __syncthreads();
    bf16x8 af[4], bfr[4];
#pragma unroll
    for (int i = 0; i < 4; ++i)
      af[i] = *(const bf16x8*)&As[(wm * 64 + i * 16 + l) * 40 + quad * 8];
#pragma unroll
    for (int j = 0; j < 4; ++j)
      bfr[j] = *(const bf16x8*)&Bs[(wn * 64 + j * 16 + l) * 40 + quad * 8];
#pragma unroll
    for (int i = 0; i < 4; ++i)
#pragma unroll
      for (int j = 0; j < 4; ++j)
        acc[i][j] = __builtin_amdgcn_mfma_f32_16x16x32_bf16(af[i], bfr[j], acc[i][j], 0, 0, 0);
    __syncthreads();
  }
#pragma unroll
  for (int i = 0; i < 4; ++i) {
    int orow = m0 + wm * 64 + i * 16 + quad * 4;
#pragma unroll
    for (int j = 0; j < 4; ++j) {
      int ncol = n0 + wn * 64 + j * 16 + l;
      __hip_bfloat16* op = w3 + ((size_t)b * CDIM + orow) * CDIM + ncol;
#pragma unroll
      for (int r = 0; r < 4; ++r) {
        float v = fminf(fmaxf(acc[i][j][r], -1.0e4f), 1.0e4f);
        op[(size_t)r * CDIM] = __float2bfloat16(v);
      }
    }
  }
}

// ---------------- legacy kernel 4: W3 GEMM ----------------
__global__ __launch_bounds__(256) void w3_gemm_kernel(
    const __hip_bfloat16* __restrict__ w2, const void* __restrict__ wqkv,
    const int* __restrict__ mode, __hip_bfloat16* __restrict__ w3) {
  const bool f32 = mode[0] != 0;
  const int b = blockIdx.z;
  const int m0 = blockIdx.y * 128;
  const int n0 = blockIdx.x * 128;
  __shared__ __align__(16) __hip_bfloat16 As[128 * 32];
  __shared__ __align__(16) __hip_bfloat16 Bs[128 * 40];
  const int tid = threadIdx.x;
  const int lane = tid & 63;
  const int wv = tid >> 6;
  const int wm = wv >> 1, wn = wv & 1;
  const int quad = lane >> 4, l = lane & 15;
  f32x4 acc[4][4] = {};
  const int nn = tid & 127;
  const int cb = tid >> 7;
  const __hip_bfloat16* wa = w2 + (size_t)b * CDIM * HID;
  for (int k0 = 0; k0 < HID; k0 += 32) {
#pragma unroll
    for (int r = 0; r < 2; ++r) {
      int idx = (r * 256 + tid) * 8;
      int row = idx >> 5, col = idx & 31;
      *(int4*)&As[idx] = *(const int4*)&wa[(size_t)(m0 + row) * HID + k0 + col];
    }
#pragma unroll
    for (int r = 0; r < 16; ++r) {
      int hdl = r * 2 + cb;
      Bs[nn * 40 + hdl] = __float2bfloat16(ldx(wqkv, (size_t)(k0 + hdl) * CDIM + n0 + nn, f32));
    }
    __syncthreads();
    bf16x8 af[4], bfr[4];
#pragma unroll
    for (int i = 0; i < 4; ++i)
      af[i] = *(const bf16x8*)&As[(wm * 64 + i * 16 + l) * 32 + quad * 8];
#pragma unroll
    for (int j = 0; j < 4; ++j)
      bfr[j] = *(const bf16x8*)&Bs[(wn * 64 + j * 16 + l) * 40 + quad * 8];
#pragma unroll
    for (int i = 0; i < 4; ++i)
#pragma unroll
      for (int j = 0; j < 4; ++j)
        acc[i][j] = __builtin_amdgcn_mfma_f32_16x16x32_bf16(af[i], bfr[j], acc[i][j], 0, 0, 0);
    __syncthreads();
  }
#pragma unroll
  for (int i = 0; i < 4; ++i) {
    int orow = m0 + wm * 64 + i * 16 + quad * 4;
#pragma unroll
    for (int j = 0; j < 4; ++j) {
      int ncol = n0 + wn * 64 + j * 16 + l;
      __hip_bfloat16* op = w3 + ((size_t)b * CDIM + orow) * CDIM + ncol;
#pragma unroll
      for (int r = 0; r < 4; ++r) {
        float v = fminf(fmaxf(acc[i][j][r], -1.0e4f), 1.0e4f);
        op[(size_t)r * CDIM] = __float2bfloat16(v);
      }
    }
  }
}

// ---------------- NEW kernel: out = W3[b] * xnormT + b_out + x (vector-staged) ----------------
__global__ __launch_bounds__(256) void out_gemm2_kernel(
    const void* __restrict__ x, const __hip_bfloat16* __restrict__ w3,
    const __hip_bfloat16* __restrict__ xnt, const int* __restrict__ mode,
    const void* __restrict__ bout, void* __restrict__ out) {
  const bool f32 = mode[0] != 0;
  const int b = blockIdx.z;
  const int m0 = blockIdx.y * 128;
  const int n0 = blockIdx.x * 128;
  __shared__ __align__(16) __hip_bfloat16 As[128 * 40];
  __shared__ __align__(16) __hip_bfloat16 Bs[128 * 40];
  const int tid = threadIdx.x;
  const int lane = tid & 63;
  const int wv = tid >> 6;
  const int wm = wv >> 1, wn = wv & 1;
  const int quad = lane >> 4, l = lane & 15;
  f32x4 acc[4][4] = {};
  const __hip_bfloat16* wa = w3 + (size_t)b * CDIM * CDIM;
  const __hip_bfloat16* xb = xnt + (size_t)b * NSEQ * CDIM;
  for (int k0 = 0; k0 < CDIM; k0 += 32) {
#pragma unroll
    for (int i = 0; i < 2; ++i) {
      int gid = tid + i * 256;
      int row = gid >> 2, c8 = (gid & 3) * 8;
      *(int4*)&As[row * 40 + c8] = *(const int4*)&wa[(size_t)(m0 + row) * CDIM + k0 + c8];
      *(int4*)&Bs[row * 40 + c8] = *(const int4*)&xb[(size_t)(n0 + row) * CDIM + k0 + c8];
    }
    __syncthreads();
    bf16x8 af[4], bfr[4];
#pragma unroll
    for (int i = 0; i < 4; ++i)
      af[i] = *(const bf16x8*)&As[(wm * 64 + i * 16 + l) * 40 + quad * 8];
#pragma unroll
    for (int j = 0; j < 4; ++j)
      bfr[j] = *(const bf16x8*)&Bs[(wn * 64 + j * 16 + l) * 40 + quad * 8];
#pragma unroll
    for (int i = 0; i < 4; ++i)
#pragma unroll
      for (int j = 0; j < 4; ++j)
        acc[i][j] = __builtin_amdgcn_mfma_f32_16x16x32_bf16(af[i], bfr[j], acc[i][j], 0, 0, 0);
    __syncthreads();
  }
#pragma unroll
  for (int i = 0; i < 4; ++i) {
    int orow = m0 + wm * 64 + i * 16 + quad * 4;
#pragma unroll
    for (int j = 0; j < 4; ++j) {
      int ncol = n0 + wn * 64 + j * 16 + l;
#pragma unroll
      for (int r = 0; r < 4; ++r) {
        size_t oi = ((size_t)b * CDIM + orow + r) * NSEQ + ncol;
        float v = acc[i][j][r] + ldx(bout, orow + r, f32) + ldx(x, oi, f32);
        stx(out, oi, f32, v);
      }
    }
  }
}

// ---------------- legacy kernel 5: out GEMM ----------------
__global__ __launch_bounds__(256) void out_gemm_kernel(
    const void* __restrict__ x, const void* __restrict__ g,
    const void* __restrict__ bln, const __hip_bfloat16* __restrict__ w3,
    const int* __restrict__ mode,
    const float* __restrict__ mean, const float* __restrict__ rstd,
    const void* __restrict__ bout, void* __restrict__ out) {
  const bool f32 = mode[0] != 0;
  const int b = blockIdx.z;
  const int m0 = blockIdx.y * 128;
  const int n0 = blockIdx.x * 128;
  __shared__ __align__(16) __hip_bfloat16 As[128 * 32];
  __shared__ __align__(16) __hip_bfloat16 Bs[128 * 40];
  const int tid = threadIdx.x;
  const int lane = tid & 63;
  const int wv = tid >> 6;
  const int wm = wv >> 1, wn = wv & 1;
  const int quad = lane >> 4, l = lane & 15;
  f32x4 acc[4][4] = {};
  const int nn = tid & 127;
  const int cb = tid >> 7;
  const float mn = mean[b * NSEQ + n0 + nn];
  const float rs = rstd[b * NSEQ + n0 + nn];
  const size_t xbase = (size_t)b * CDIM * NSEQ + n0 + nn;
  const __hip_bfloat16* wa = w3 + (size_t)b * CDIM * CDIM;
  for (int k0 = 0; k0 < CDIM; k0 += 32) {
#pragma unroll
    for (int r = 0; r < 2; ++r) {
      int idx = (r * 256 + tid) * 8;
      int row = idx >> 5, col = idx & 31;
      *(int4*)&As[idx] = *(const int4*)&wa[(size_t)(m0 + row) * CDIM + k0 + col];
    }
#pragma unroll
    for (int r = 0; r < 16; ++r) {
      int c = r * 2 + cb;
      float xv = ldx(x, xbase + (size_t)(k0 + c) * NSEQ, f32);
      float xn = (xv - mn) * rs;
      xn = xn * ldx(g, k0 + c, f32) + ldx(bln, k0 + c, f32);
      Bs[nn * 40 + c] = __float2bfloat16(xn);
    }
    __syncthreads();
    bf16x8 af[4], bfr[4];
#pragma unroll
    for (int i = 0; i < 4; ++i)
      af[i] = *(const bf16x8*)&As[(wm * 64 + i * 16 + l) * 32 + quad * 8];
#pragma unroll
    for (int j = 0; j < 4; ++j)
      bfr[j] = *(const bf16x8*)&Bs[(wn * 64 + j * 16 + l) * 40 + quad * 8];
#pragma unroll
    for (int i = 0; i < 4; ++i)
#pragma unroll
      for (int j = 0; j < 4; ++j)
        acc[i][j] = __builtin_amdgcn_mfma_f32_16x16x32_bf16(af[i], bfr[j], acc[i][j], 0, 0, 0);
    __syncthreads();
  }
#pragma unroll
  for (int i = 0; i < 4; ++i) {
    int orow = m0 + wm * 64 + i * 16 + quad * 4;
#pragma unroll
    for (int j = 0; j < 4; ++j) {
      int ncol = n0 + wn * 64 + j * 16 + l;
#pragma unroll
      for (int r = 0; r < 4; ++r) {
        size_t oi = ((size_t)b * CDIM + orow + r) * NSEQ + ncol;
        float v = acc[i][j][r] + ldx(bout, orow + r, f32) + ldx(x, oi, f32);
        stx(out, oi, f32, v);
      }
    }
  }
}

extern "C" void kernel_launch(void* const* d_in, const int* in_sizes, int n_in,
                              void* d_out, int out_size, void* d_ws, size_t ws_size,
                              hipStream_t stream) {
  (void)in_sizes; (void)n_in; (void)out_size;
  const void* x    = d_in[0];
  const void* g    = d_in[1];
  const void* bln  = d_in[2];
  const void* wqkv = d_in[3];
  const void* wout = d_in[4];
  const void* bout = d_in[5];

  // workspace layout: legacy prefix (~7 MB) + bf16 wqkv copy + bf16 xnormT (~72 MB total)
  float* mean   = (float*)d_ws;                    // 8*8192
  float* rstd   = mean + BATCH * NSEQ;             // 8*8192
  float* ctxb   = rstd + BATCH * NSEQ;             // 65536
  float* sumexp = ctxb + BATCH * HEADS * DH * DH;  // 2048
  int*   mode   = (int*)(sumexp + BATCH * HEADS * DH);
  __hip_bfloat16* w2  = (__hip_bfloat16*)(mode + 64);            // 8*512*256
  __hip_bfloat16* w3  = w2 + (size_t)BATCH * CDIM * HID;         // 8*512*512
  __hip_bfloat16* wb  = w3 + (size_t)BATCH * CDIM * CDIM;        // 768*512
  __hip_bfloat16* xnt = wb + (size_t)O3 * CDIM;                  // 8*8192*512
  const size_t need = (size_t)((const char*)(xnt + (size_t)BATCH * NSEQ * CDIM) - (const char*)d_ws);

  hipMemsetAsync(ctxb, 0, (BATCH * HEADS * DH * DH + BATCH * HEADS * DH) * sizeof(float), stream);
  detect_kernel<<<1, 256, 0, stream>>>(x, mode);

  if (ws_size >= need) {
    // fast path: precompute xnormT (bf16, [b][n][c]) + bf16 weights; vector-staged GEMMs
    ln_stats4_kernel<<<dim3(NSEQ / 128, BATCH), 256, 0, stream>>>(x, mode, mean, rstd);
    wconv_kernel<<<dim3((O3 * CDIM) / 2048), 256, 0, stream>>>(wqkv, mode, wb);
    xnormt_kernel<<<dim3(NSEQ / 128, CDIM / 128, BATCH), 256, 0, stream>>>(
        x, g, bln, mode, mean, rstd, xnt);
    kv_gemm2_kernel<<<dim3(NSEQ / 128, HEADS / 2, BATCH), 256, 0, stream>>>(
        wb, xnt, ctxb, sumexp);
    w2_build_kernel<<<dim3(CDIM, BATCH), 256, 0, stream>>>(wout, mode, ctxb, sumexp, w2);
    w3_gemm2_kernel<<<dim3(CDIM / 128, CDIM / 128, BATCH), 256, 0, stream>>>(w2, wb, w3);
    out_gemm2_kernel<<<dim3(NSEQ / 128, CDIM / 128, BATCH), 256, 0, stream>>>(
        x, w3, xnt, mode, bout, d_out);
  } else {
    // legacy verified path (~7 MB workspace)
    ln_stats_kernel<<<dim3(NSEQ / 64, BATCH), 256, 0, stream>>>(x, mode, mean, rstd);
    kvctx_kernel<<<dim3(NSEQ / 128, HEADS / 2, BATCH), 256, 0, stream>>>(
        x, g, bln, wqkv, mode, mean, rstd, ctxb, sumexp);
    w2_build_kernel<<<dim3(CDIM, BATCH), 256, 0, stream>>>(wout, mode, ctxb, sumexp, w2);
    w3_gemm_kernel<<<dim3(CDIM / 128, CDIM / 128, BATCH), 256, 0, stream>>>(w2, wqkv, mode, w3);
    out_gemm_kernel<<<dim3(NSEQ / 128, CDIM / 128, BATCH), 256, 0, stream>>>(
        x, g, bln, w3, mode, mean, rstd, bout, d_out);
  }
}

// Round 2
// 593.581 us; speedup vs baseline: 2.1292x; 1.0601x over previous
//
#include <hip/hip_runtime.h>
#include <hip/hip_bf16.h>
#include <math.h>

#define HEADS 8
#define DH 32
#define BATCH 8
#define CDIM 512
#define NSEQ 8192
#define HID 256
#define O3 768
#define LNEPS 1e-5f
#define QSCALE 0.1767766952966369f  // 32^-0.5

typedef __bf16 bf16x8 __attribute__((ext_vector_type(8)));
typedef float f32x4 __attribute__((ext_vector_type(4)));
typedef unsigned short u16;
typedef u16 u16x4 __attribute__((ext_vector_type(4)));
typedef u16 u16x8 __attribute__((ext_vector_type(8)));

// async global->LDS 16B copy: LDS dest is wave-uniform base + lane*16 (m97 pattern)
__device__ __forceinline__ void gld_lds16(const void* g, void* l) {
  __builtin_amdgcn_global_load_lds(
      (const __attribute__((address_space(1))) unsigned int*)g,
      (__attribute__((address_space(3))) unsigned int*)l, 16, 0, 0);
}

// dual-dtype element load: mode==1 -> fp32 buffer, mode==0 -> bf16 buffer
__device__ __forceinline__ float ldx(const void* p, size_t i, bool f32) {
  if (f32) {
    float v = ((const float*)p)[i];
    return __builtin_isfinite(v) ? v : 0.f;
  }
  return __bfloat162float(((const __hip_bfloat16*)p)[i]);
}

__device__ __forceinline__ u16 b16(float v) {
  union { __hip_bfloat16 h; u16 u; } cv;
  cv.h = __float2bfloat16(v);
  return cv.u;
}

__device__ __forceinline__ float fb16(u16 u) {
  return __uint_as_float((unsigned)u << 16);
}

// stage 8 contiguous elements into LDS as bf16 (legacy path)
__device__ __forceinline__ void stage8(__hip_bfloat16* dst, const void* src, size_t idx, bool f32) {
  if (f32) {
    const float* s = (const float*)src + idx;
#pragma unroll
    for (int t = 0; t < 8; ++t) {
      float v = s[t];
      if (!__builtin_isfinite(v)) v = 0.f;
      dst[t] = __float2bfloat16(v);
    }
  } else {
    *(int4*)dst = *(const int4*)((const __hip_bfloat16*)src + idx);
  }
}

// dual-dtype store with finite scrub
__device__ __forceinline__ void stx(void* p, size_t i, bool f32, float v) {
  if (!__builtin_isfinite(v)) v = 0.f;
  if (f32) ((float*)p)[i] = v;
  else ((__hip_bfloat16*)p)[i] = __float2bfloat16(v);
}

// ---------------- kernel 0: dtype detector ----------------
__global__ __launch_bounds__(256) void detect_kernel(const void* __restrict__ x, int* __restrict__ mode) {
  __shared__ int cnt;
  if (threadIdx.x == 0) cnt = 0;
  __syncthreads();
  const __hip_bfloat16* p = (const __hip_bfloat16*)x;
  int c = 0;
  for (int i = threadIdx.x; i < 4096; i += 256) {
    float v = __bfloat162float(p[i]);
    if (!(v > -1.0e3f && v < 1.0e3f)) c++;
  }
  atomicAdd(&cnt, c);
  __syncthreads();
  if (threadIdx.x == 0) mode[0] = (cnt > 64) ? 1 : 0;
}

// ---------------- LN stats, float4-vectorized ----------------
__global__ __launch_bounds__(256) void ln_stats4_kernel(
    const void* __restrict__ x, const int* __restrict__ mode,
    float* __restrict__ mean, float* __restrict__ rstd) {
  const bool f32 = mode[0] != 0;
  const int b = blockIdx.y;
  const int n0 = blockIdx.x * 128;
  const int t = threadIdx.x;
  const int m = t & 31, cp = t >> 5;
  const int n4 = m * 4;
  const size_t base = (size_t)b * CDIM * NSEQ + n0 + n4;
  f32x4 s = {0.f, 0.f, 0.f, 0.f}, q = {0.f, 0.f, 0.f, 0.f};
  for (int c = cp * 64; c < cp * 64 + 64; ++c) {
    f32x4 v;
    if (f32) {
      v = *(const f32x4*)((const float*)x + base + (size_t)c * NSEQ);
#pragma unroll
      for (int j = 0; j < 4; ++j) if (!__builtin_isfinite(v[j])) v[j] = 0.f;
    } else {
      u16x4 h = *(const u16x4*)((const __hip_bfloat16*)x + base + (size_t)c * NSEQ);
#pragma unroll
      for (int j = 0; j < 4; ++j) v[j] = fb16(h[j]);
    }
    s += v;
    q += v * v;
  }
  __shared__ f32x4 sbS[8][32], sbQ[8][32];
  sbS[cp][m] = s; sbQ[cp][m] = q;
  __syncthreads();
  if (t < 32) {
    f32x4 S = sbS[0][t], Q = sbQ[0][t];
#pragma unroll
    for (int k = 1; k < 8; ++k) { S += sbS[k][t]; Q += sbQ[k][t]; }
    f32x4 M = S * (1.f / CDIM);
    f32x4 V = Q * (1.f / CDIM) - M * M;
#pragma unroll
    for (int j = 0; j < 4; ++j) {
      mean[b * NSEQ + n0 + t * 4 + j] = M[j];
      rstd[b * NSEQ + n0 + t * 4 + j] = rsqrtf(fmaxf(V[j], 0.f) + LNEPS);
    }
  }
}

// ---------------- wqkv -> bf16 once ----------------
__global__ __launch_bounds__(256) void wconv_kernel(
    const void* __restrict__ wqkv, const int* __restrict__ mode,
    __hip_bfloat16* __restrict__ wb) {
  const bool f32 = mode[0] != 0;
  const size_t i = ((size_t)blockIdx.x * 256 + threadIdx.x) * 8;
  if (f32) {
    f32x4 a = *(const f32x4*)((const float*)wqkv + i);
    f32x4 c = *(const f32x4*)((const float*)wqkv + i + 4);
    u16x8 o;
#pragma unroll
    for (int j = 0; j < 4; ++j) {
      float va = __builtin_isfinite(a[j]) ? a[j] : 0.f;
      float vc = __builtin_isfinite(c[j]) ? c[j] : 0.f;
      o[j] = b16(va);
      o[4 + j] = b16(vc);
    }
    *(u16x8*)&wb[i] = o;
  } else {
    *(int4*)&wb[i] = *(const int4*)((const __hip_bfloat16*)wqkv + i);
  }
}

// ---------------- xnormT[b][n][c] bf16 via LDS transpose ----------------
__global__ __launch_bounds__(256) void xnormt_kernel(
    const void* __restrict__ x, const void* __restrict__ g, const void* __restrict__ bln,
    const int* __restrict__ mode, const float* __restrict__ mean, const float* __restrict__ rstd,
    __hip_bfloat16* __restrict__ xnt) {
  const bool f32 = mode[0] != 0;
  const int b = blockIdx.z;
  const int c0 = blockIdx.y * 128;
  const int n0 = blockIdx.x * 128;
  __shared__ u16 tile[128 * 132];
  const int t = threadIdx.x;
  const int m = t & 31, rb = t >> 5;
  const int n4 = m * 4;
  const f32x4 mn = *(const f32x4*)&mean[b * NSEQ + n0 + n4];
  const f32x4 rs = *(const f32x4*)&rstd[b * NSEQ + n0 + n4];
#pragma unroll
  for (int it = 0; it < 16; ++it) {
    const int r = it * 8 + rb;
    const float gv = ldx(g, c0 + r, f32);
    const float bv = ldx(bln, c0 + r, f32);
    const size_t src = ((size_t)b * CDIM + c0 + r) * NSEQ + n0 + n4;
    f32x4 v;
    if (f32) {
      v = *(const f32x4*)((const float*)x + src);
#pragma unroll
      for (int j = 0; j < 4; ++j) if (!__builtin_isfinite(v[j])) v[j] = 0.f;
    } else {
      u16x4 h = *(const u16x4*)((const __hip_bfloat16*)x + src);
#pragma unroll
      for (int j = 0; j < 4; ++j) v[j] = fb16(h[j]);
    }
    u16x4 o;
#pragma unroll
    for (int j = 0; j < 4; ++j) o[j] = b16((v[j] - mn[j]) * rs[j] * gv + bv);
    *(u16x4*)&tile[r * 132 + n4] = o;
  }
  __syncthreads();
  const int n = t >> 1, ch = t & 1;
  __hip_bfloat16* dst = xnt + ((size_t)b * NSEQ + n0 + n) * CDIM + c0 + ch * 64;
#pragma unroll
  for (int i8 = 0; i8 < 8; ++i8) {
    u16x8 o;
#pragma unroll
    for (int k = 0; k < 8; ++k) o[k] = tile[(ch * 64 + i8 * 8 + k) * 132 + n];
    *(u16x8*)(dst + i8 * 8) = o;
  }
}

// ---------------- legacy kernel 1: LayerNorm stats ----------------
__global__ __launch_bounds__(256) void ln_stats_kernel(
    const void* __restrict__ x, const int* __restrict__ mode,
    float* __restrict__ mean, float* __restrict__ rstd) {
  const bool f32 = mode[0] != 0;
  int b = blockIdx.y;
  int nl = threadIdx.x & 63;
  int cp = threadIdx.x >> 6;
  int n = blockIdx.x * 64 + nl;
  size_t base = (size_t)b * CDIM * NSEQ + n;
  float s = 0.f, ss = 0.f;
  for (int c = cp * 128; c < cp * 128 + 128; ++c) {
    float v = ldx(x, base + (size_t)c * NSEQ, f32);
    s += v; ss += v * v;
  }
  __shared__ float sb[4][64], sb2[4][64];
  sb[cp][nl] = s; sb2[cp][nl] = ss;
  __syncthreads();
  if (cp == 0) {
    s = sb[0][nl] + sb[1][nl] + sb[2][nl] + sb[3][nl];
    ss = sb2[0][nl] + sb2[1][nl] + sb2[2][nl] + sb2[3][nl];
    float m = s * (1.f / CDIM);
    float var = ss * (1.f / CDIM) - m * m;
    mean[b * NSEQ + n] = m;
    rstd[b * NSEQ + n] = rsqrtf(fmaxf(var, 0.f) + LNEPS);
  }
}

// ---------------- K/V GEMM + exp + context, global_load_lds staging ----------------
__global__ __launch_bounds__(256) void kv_gemm3_kernel(
    const __hip_bfloat16* __restrict__ wb, const __hip_bfloat16* __restrict__ xnt,
    float* __restrict__ ctxb, float* __restrict__ sumexp) {
  const int b = blockIdx.z;
  const int p = blockIdx.y;
  const int n0 = blockIdx.x * 128;
  __shared__ __align__(16) char smem[128 * 136 * 2];  // union: As+Bs (16KB linear) / Ct (34KB)
  __hip_bfloat16* As = (__hip_bfloat16*)smem;          // [128][32] linear
  __hip_bfloat16* Bs = As + 128 * 32;                  // [128][32] linear
  __hip_bfloat16* Ct = (__hip_bfloat16*)smem;
  const int tid = threadIdx.x;
  const int lane = tid & 63;
  const int wv = tid >> 6;
  const int wm = wv >> 1, wn = wv & 1;
  const int quad = lane >> 4, l = lane & 15;
  f32x4 acc[4][4] = {};
  const __hip_bfloat16* xb = xnt + (size_t)b * NSEQ * CDIM;
  // per-lane source geometry for global_load_lds (lane covers row = c*64 + wv*16 + (lane>>2))
  const int lr = lane >> 2, lc8 = (lane & 3) * 8;
  for (int k0 = 0; k0 < CDIM; k0 += 32) {
#pragma unroll
    for (int c = 0; c < 2; ++c) {
      int row = c * 64 + wv * 16 + lr;
      int srow = (row < 64) ? (256 + p * 64 + row) : (512 + p * 64 + row - 64);
      gld_lds16(&wb[(size_t)srow * CDIM + k0 + lc8], &As[(c * 64 + wv * 16) * 32]);
      gld_lds16(&xb[(size_t)(n0 + row) * CDIM + k0 + lc8], &Bs[(c * 64 + wv * 16) * 32]);
    }
    __syncthreads();
    bf16x8 af[4], bfr[4];
#pragma unroll
    for (int i = 0; i < 4; ++i)
      af[i] = *(const bf16x8*)&As[(wm * 64 + i * 16 + l) * 32 + quad * 8];
#pragma unroll
    for (int j = 0; j < 4; ++j)
      bfr[j] = *(const bf16x8*)&Bs[(wn * 64 + j * 16 + l) * 32 + quad * 8];
#pragma unroll
    for (int i = 0; i < 4; ++i)
#pragma unroll
      for (int j = 0; j < 4; ++j)
        acc[i][j] = __builtin_amdgcn_mfma_f32_16x16x32_bf16(af[i], bfr[j], acc[i][j], 0, 0, 0);
    __syncthreads();
  }
  // epilogue: exp on K half (rows 0..63), clamp V half; write C tile to LDS
#pragma unroll
  for (int i = 0; i < 4; ++i) {
    int row = wm * 64 + i * 16 + quad * 4;
#pragma unroll
    for (int j = 0; j < 4; ++j) {
      int col = wn * 64 + j * 16 + l;
#pragma unroll
      for (int r = 0; r < 4; ++r) {
        float v = acc[i][j][r];
        if (wm == 0) v = expf(fminf(v, 20.f));
        else         v = fminf(fmaxf(v, -1.0e4f), 1.0e4f);
        Ct[(row + r) * 136 + col] = __float2bfloat16(v);
      }
    }
  }
  __syncthreads();
  const int mi = wm, ni = wn;
#pragma unroll
  for (int hh = 0; hh < 2; ++hh) {
    f32x4 ca = {};
#pragma unroll
    for (int ks = 0; ks < 4; ++ks) {
      bf16x8 ea = *(const bf16x8*)&Ct[(hh * 32 + mi * 16 + l) * 136 + ks * 32 + quad * 8];
      bf16x8 vb = *(const bf16x8*)&Ct[(64 + hh * 32 + ni * 16 + l) * 136 + ks * 32 + quad * 8];
      ca = __builtin_amdgcn_mfma_f32_16x16x32_bf16(ea, vb, ca, 0, 0, 0);
    }
    int h = p * 2 + hh;
    float* cp = ctxb + (size_t)(b * HEADS + h) * DH * DH;
#pragma unroll
    for (int r = 0; r < 4; ++r)
      atomicAdd(&cp[(mi * 16 + quad * 4 + r) * DH + ni * 16 + l], ca[r]);
  }
  if (tid < 64) {
    int hh = tid >> 5, d = tid & 31;
    float s = 0.f;
#pragma unroll 16
    for (int c = 0; c < 128; ++c) s += __bfloat162float(Ct[tid * 136 + c]);
    atomicAdd(&sumexp[(b * HEADS + p * 2 + hh) * DH + d], s);
  }
}

// ---------------- legacy kernel 2: fused K/V GEMM + exp + context ----------------
__global__ __launch_bounds__(256) void kvctx_kernel(
    const void* __restrict__ x, const void* __restrict__ g,
    const void* __restrict__ bln, const void* __restrict__ wqkv,
    const int* __restrict__ mode,
    const float* __restrict__ mean, const float* __restrict__ rstd,
    float* __restrict__ ctxb, float* __restrict__ sumexp) {
  const bool f32 = mode[0] != 0;
  const int b = blockIdx.z;
  const int p = blockIdx.y;
  const int n0 = blockIdx.x * 128;
  __shared__ __align__(16) __hip_bfloat16 As[128 * 32];
  __shared__ __align__(16) __hip_bfloat16 Bs[128 * 40];
  __shared__ __align__(16) __hip_bfloat16 Ct[128 * 136];
  const int tid = threadIdx.x;
  const int lane = tid & 63;
  const int wv = tid >> 6;
  const int wm = wv >> 1, wn = wv & 1;
  const int quad = lane >> 4, l = lane & 15;
  f32x4 acc[4][4] = {};
  const int nn = tid & 127;
  const int cb = tid >> 7;
  const float mn = mean[b * NSEQ + n0 + nn];
  const float rs = rstd[b * NSEQ + n0 + nn];
  const size_t xbase = (size_t)b * CDIM * NSEQ + n0 + nn;
  for (int k0 = 0; k0 < CDIM; k0 += 32) {
#pragma unroll
    for (int r = 0; r < 2; ++r) {
      int idx = (r * 256 + tid) * 8;
      int row = idx >> 5, col = idx & 31;
      int srow = (row < 64) ? (256 + p * 64 + row) : (512 + p * 64 + row - 64);
      stage8(&As[idx], wqkv, (size_t)srow * CDIM + k0 + col, f32);
    }
#pragma unroll
    for (int r = 0; r < 16; ++r) {
      int c = r * 2 + cb;
      float xv = ldx(x, xbase + (size_t)(k0 + c) * NSEQ, f32);
      float xn = (xv - mn) * rs;
      xn = xn * ldx(g, k0 + c, f32) + ldx(bln, k0 + c, f32);
      Bs[nn * 40 + c] = __float2bfloat16(xn);
    }
    __syncthreads();
    bf16x8 af[4], bfr[4];
#pragma unroll
    for (int i = 0; i < 4; ++i)
      af[i] = *(const bf16x8*)&As[(wm * 64 + i * 16 + l) * 32 + quad * 8];
#pragma unroll
    for (int j = 0; j < 4; ++j)
      bfr[j] = *(const bf16x8*)&Bs[(wn * 64 + j * 16 + l) * 40 + quad * 8];
#pragma unroll
    for (int i = 0; i < 4; ++i)
#pragma unroll
      for (int j = 0; j < 4; ++j)
        acc[i][j] = __builtin_amdgcn_mfma_f32_16x16x32_bf16(af[i], bfr[j], acc[i][j], 0, 0, 0);
    __syncthreads();
  }
#pragma unroll
  for (int i = 0; i < 4; ++i) {
    int row = wm * 64 + i * 16 + quad * 4;
#pragma unroll
    for (int j = 0; j < 4; ++j) {
      int col = wn * 64 + j * 16 + l;
#pragma unroll
      for (int r = 0; r < 4; ++r) {
        float v = acc[i][j][r];
        if (wm == 0) v = expf(fminf(v, 20.f));
        else         v = fminf(fmaxf(v, -1.0e4f), 1.0e4f);
        Ct[(row + r) * 136 + col] = __float2bfloat16(v);
      }
    }
  }
  __syncthreads();
  const int mi = wm, ni = wn;
#pragma unroll
  for (int hh = 0; hh < 2; ++hh) {
    f32x4 ca = {};
#pragma unroll
    for (int ks = 0; ks < 4; ++ks) {
      bf16x8 ea = *(const bf16x8*)&Ct[(hh * 32 + mi * 16 + l) * 136 + ks * 32 + quad * 8];
      bf16x8 vb = *(const bf16x8*)&Ct[(64 + hh * 32 + ni * 16 + l) * 136 + ks * 32 + quad * 8];
      ca = __builtin_amdgcn_mfma_f32_16x16x32_bf16(ea, vb, ca, 0, 0, 0);
    }
    int h = p * 2 + hh;
    float* cp = ctxb + (size_t)(b * HEADS + h) * DH * DH;
#pragma unroll
    for (int r = 0; r < 4; ++r)
      atomicAdd(&cp[(mi * 16 + quad * 4 + r) * DH + ni * 16 + l], ca[r]);
  }
  if (tid < 64) {
    int hh = tid >> 5, d = tid & 31;
    float s = 0.f;
#pragma unroll 16
    for (int c = 0; c < 128; ++c) s += __bfloat162float(Ct[tid * 136 + c]);
    atomicAdd(&sumexp[(b * HEADS + p * 2 + hh) * DH + d], s);
  }
}

// ---------------- kernel 3: W2 build (clamped) ----------------
__global__ __launch_bounds__(256) void w2_build_kernel(
    const void* __restrict__ wout, const int* __restrict__ mode,
    const float* __restrict__ ctxb, const float* __restrict__ sumexp,
    __hip_bfloat16* __restrict__ w2) {
  const bool f32 = mode[0] != 0;
  const int o = blockIdx.x;
  const int b = blockIdx.y;
  const int hd = threadIdx.x;
  const int h = hd >> 5, d = hd & 31;
  const float* cp = ctxb + ((size_t)(b * HEADS + h) * DH + d) * DH;
  float a = 0.f;
#pragma unroll
  for (int e = 0; e < DH; ++e) a += ldx(wout, (size_t)o * HID + h * DH + e, f32) * cp[e];
  float se = fmaxf(sumexp[(b * HEADS + h) * DH + d], 1e-30f);
  float v = a * QSCALE / se;
  v = fminf(fmaxf(v, -1.0e3f), 1.0e3f);
  w2[((size_t)b * CDIM + o) * HID + hd] = __float2bfloat16(v);
}

// ---------------- W3[b] = W2[b] (512x256) * Wq (256x512), bf16 sources ----------------
__global__ __launch_bounds__(256) void w3_gemm2_kernel(
    const __hip_bfloat16* __restrict__ w2, const __hip_bfloat16* __restrict__ wb,
    __hip_bfloat16* __restrict__ w3) {
  const int b = blockIdx.z;
  const int m0 = blockIdx.y * 128;
  const int n0 = blockIdx.x * 128;
  __shared__ __align__(16) __hip_bfloat16 As[128 * 40];
  __shared__ __align__(16) __hip_bfloat16 Bs[128 * 40];
  const int tid = threadIdx.x;
  const int lane = tid & 63;
  const int wv = tid >> 6;
  const int wm = wv >> 1, wn = wv & 1;
  const int quad = lane >> 4, l = lane & 15;
  f32x4 acc[4][4] = {};
  const int nn = tid & 127;
  const int cb = tid >> 7;
  const __hip_bfloat16* wa = w2 + (size_t)b * CDIM * HID;
  for (int k0 = 0; k0 < HID; k0 += 32) {
#pragma unroll
    for (int i = 0; i < 2; ++i) {
      int gid = tid + i * 256;
      int row = gid >> 2, c8 = (gid & 3) * 8;
      *(int4*)&As[row * 40 + c8] = *(const int4*)&wa[(size_t)(m0 + row) * HID + k0 + c8];
    }
#pragma unroll
    for (int r = 0; r < 16; ++r) {
      int hdl = r * 2 + cb;
      Bs[nn * 40 + hdl] = wb[(size_t)(k0 + hdl) * CDIM + n0 + nn];
    }
    __syncthreads();
    bf16x8 af[4], bfr[4];
#pragma unroll
    for (int i = 0; i < 4; ++i)
      af[i] = *(const bf16x8*)&As[(wm * 64 + i * 16 + l) * 40 + quad * 8];
#pragma unroll
    for (int j = 0; j < 4; ++j)
      bfr[j] = *(const bf16x8*)&Bs[(wn * 64 + j * 16 + l) * 40 + quad * 8];
#pragma unroll
    for (int i = 0; i < 4; ++i)
#pragma unroll
      for (int j = 0; j < 4; ++j)
        acc[i][j] = __builtin_amdgcn_mfma_f32_16x16x32_bf16(af[i], bfr[j], acc[i][j], 0, 0, 0);
    __syncthreads();
  }
#pragma unroll
  for (int i = 0; i < 4; ++i) {
    int orow = m0 + wm * 64 + i * 16 + quad * 4;
#pragma unroll
    for (int j = 0; j < 4; ++j) {
      int ncol = n0 + wn * 64 + j * 16 + l;
      __hip_bfloat16* op = w3 + ((size_t)b * CDIM + orow) * CDIM + ncol;
#pragma unroll
      for (int r = 0; r < 4; ++r) {
        float v = fminf(fmaxf(acc[i][j][r], -1.0e4f), 1.0e4f);
        op[(size_t)r * CDIM] = __float2bfloat16(v);
      }
    }
  }
}

// ---------------- legacy kernel 4: W3 GEMM ----------------
__global__ __launch_bounds__(256) void w3_gemm_kernel(
    const __hip_bfloat16* __restrict__ w2, const void* __restrict__ wqkv,
    const int* __restrict__ mode, __hip_bfloat16* __restrict__ w3) {
  const bool f32 = mode[0] != 0;
  const int b = blockIdx.z;
  const int m0 = blockIdx.y * 128;
  const int n0 = blockIdx.x * 128;
  __shared__ __align__(16) __hip_bfloat16 As[128 * 32];
  __shared__ __align__(16) __hip_bfloat16 Bs[128 * 40];
  const int tid = threadIdx.x;
  const int lane = tid & 63;
  const int wv = tid >> 6;
  const int wm = wv >> 1, wn = wv & 1;
  const int quad = lane >> 4, l = lane & 15;
  f32x4 acc[4][4] = {};
  const int nn = tid & 127;
  const int cb = tid >> 7;
  const __hip_bfloat16* wa = w2 + (size_t)b * CDIM * HID;
  for (int k0 = 0; k0 < HID; k0 += 32) {
#pragma unroll
    for (int r = 0; r < 2; ++r) {
      int idx = (r * 256 + tid) * 8;
      int row = idx >> 5, col = idx & 31;
      *(int4*)&As[idx] = *(const int4*)&wa[(size_t)(m0 + row) * HID + k0 + col];
    }
#pragma unroll
    for (int r = 0; r < 16; ++r) {
      int hdl = r * 2 + cb;
      Bs[nn * 40 + hdl] = __float2bfloat16(ldx(wqkv, (size_t)(k0 + hdl) * CDIM + n0 + nn, f32));
    }
    __syncthreads();
    bf16x8 af[4], bfr[4];
#pragma unroll
    for (int i = 0; i < 4; ++i)
      af[i] = *(const bf16x8*)&As[(wm * 64 + i * 16 + l) * 32 + quad * 8];
#pragma unroll
    for (int j = 0; j < 4; ++j)
      bfr[j] = *(const bf16x8*)&Bs[(wn * 64 + j * 16 + l) * 40 + quad * 8];
#pragma unroll
    for (int i = 0; i < 4; ++i)
#pragma unroll
      for (int j = 0; j < 4; ++j)
        acc[i][j] = __builtin_amdgcn_mfma_f32_16x16x32_bf16(af[i], bfr[j], acc[i][j], 0, 0, 0);
    __syncthreads();
  }
#pragma unroll
  for (int i = 0; i < 4; ++i) {
    int orow = m0 + wm * 64 + i * 16 + quad * 4;
#pragma unroll
    for (int j = 0; j < 4; ++j) {
      int ncol = n0 + wn * 64 + j * 16 + l;
      __hip_bfloat16* op = w3 + ((size_t)b * CDIM + orow) * CDIM + ncol;
#pragma unroll
      for (int r = 0; r < 4; ++r) {
        float v = fminf(fmaxf(acc[i][j][r], -1.0e4f), 1.0e4f);
        op[(size_t)r * CDIM] = __float2bfloat16(v);
      }
    }
  }
}

// ---------------- out = W3[b] * xnormT + b_out + x, global_load_lds staging ----------------
__global__ __launch_bounds__(256) void out_gemm3_kernel(
    const void* __restrict__ x, const __hip_bfloat16* __restrict__ w3,
    const __hip_bfloat16* __restrict__ xnt, const int* __restrict__ mode,
    const void* __restrict__ bout, void* __restrict__ out) {
  const bool f32 = mode[0] != 0;
  const int b = blockIdx.z;
  const int m0 = blockIdx.y * 128;
  const int n0 = blockIdx.x * 128;
  __shared__ __align__(16) __hip_bfloat16 As[128 * 32];  // linear
  __shared__ __align__(16) __hip_bfloat16 Bs[128 * 32];  // linear
  const int tid = threadIdx.x;
  const int lane = tid & 63;
  const int wv = tid >> 6;
  const int wm = wv >> 1, wn = wv & 1;
  const int quad = lane >> 4, l = lane & 15;
  f32x4 acc[4][4] = {};
  const __hip_bfloat16* wa = w3 + (size_t)b * CDIM * CDIM;
  const __hip_bfloat16* xb = xnt + (size_t)b * NSEQ * CDIM;
  const int lr = lane >> 2, lc8 = (lane & 3) * 8;
  for (int k0 = 0; k0 < CDIM; k0 += 32) {
#pragma unroll
    for (int c = 0; c < 2; ++c) {
      int row = c * 64 + wv * 16 + lr;
      gld_lds16(&wa[(size_t)(m0 + row) * CDIM + k0 + lc8], &As[(c * 64 + wv * 16) * 32]);
      gld_lds16(&xb[(size_t)(n0 + row) * CDIM + k0 + lc8], &Bs[(c * 64 + wv * 16) * 32]);
    }
    __syncthreads();
    bf16x8 af[4], bfr[4];
#pragma unroll
    for (int i = 0; i < 4; ++i)
      af[i] = *(const bf16x8*)&As[(wm * 64 + i * 16 + l) * 32 + quad * 8];
#pragma unroll
    for (int j = 0; j < 4; ++j)
      bfr[j] = *(const bf16x8*)&Bs[(wn * 64 + j * 16 + l) * 32 + quad * 8];
#pragma unroll
    for (int i = 0; i < 4; ++i)
#pragma unroll
      for (int j = 0; j < 4; ++j)
        acc[i][j] = __builtin_amdgcn_mfma_f32_16x16x32_bf16(af[i], bfr[j], acc[i][j], 0, 0, 0);
    __syncthreads();
  }
#pragma unroll
  for (int i = 0; i < 4; ++i) {
    int orow = m0 + wm * 64 + i * 16 + quad * 4;
#pragma unroll
    for (int j = 0; j < 4; ++j) {
      int ncol = n0 + wn * 64 + j * 16 + l;
#pragma unroll
      for (int r = 0; r < 4; ++r) {
        size_t oi = ((size_t)b * CDIM + orow + r) * NSEQ + ncol;
        float v = acc[i][j][r] + ldx(bout, orow + r, f32) + ldx(x, oi, f32);
        stx(out, oi, f32, v);
      }
    }
  }
}

// ---------------- legacy kernel 5: out GEMM ----------------
__global__ __launch_bounds__(256) void out_gemm_kernel(
    const void* __restrict__ x, const void* __restrict__ g,
    const void* __restrict__ bln, const __hip_bfloat16* __restrict__ w3,
    const int* __restrict__ mode,
    const float* __restrict__ mean, const float* __restrict__ rstd,
    const void* __restrict__ bout, void* __restrict__ out) {
  const bool f32 = mode[0] != 0;
  const int b = blockIdx.z;
  const int m0 = blockIdx.y * 128;
  const int n0 = blockIdx.x * 128;
  __shared__ __align__(16) __hip_bfloat16 As[128 * 32];
  __shared__ __align__(16) __hip_bfloat16 Bs[128 * 40];
  const int tid = threadIdx.x;
  const int lane = tid & 63;
  const int wv = tid >> 6;
  const int wm = wv >> 1, wn = wv & 1;
  const int quad = lane >> 4, l = lane & 15;
  f32x4 acc[4][4] = {};
  const int nn = tid & 127;
  const int cb = tid >> 7;
  const float mn = mean[b * NSEQ + n0 + nn];
  const float rs = rstd[b * NSEQ + n0 + nn];
  const size_t xbase = (size_t)b * CDIM * NSEQ + n0 + nn;
  const __hip_bfloat16* wa = w3 + (size_t)b * CDIM * CDIM;
  for (int k0 = 0; k0 < CDIM; k0 += 32) {
#pragma unroll
    for (int r = 0; r < 2; ++r) {
      int idx = (r * 256 + tid) * 8;
      int row = idx >> 5, col = idx & 31;
      *(int4*)&As[idx] = *(const int4*)&wa[(size_t)(m0 + row) * CDIM + k0 + col];
    }
#pragma unroll
    for (int r = 0; r < 16; ++r) {
      int c = r * 2 + cb;
      float xv = ldx(x, xbase + (size_t)(k0 + c) * NSEQ, f32);
      float xn = (xv - mn) * rs;
      xn = xn * ldx(g, k0 + c, f32) + ldx(bln, k0 + c, f32);
      Bs[nn * 40 + c] = __float2bfloat16(xn);
    }
    __syncthreads();
    bf16x8 af[4], bfr[4];
#pragma unroll
    for (int i = 0; i < 4; ++i)
      af[i] = *(const bf16x8*)&As[(wm * 64 + i * 16 + l) * 32 + quad * 8];
#pragma unroll
    for (int j = 0; j < 4; ++j)
      bfr[j] = *(const bf16x8*)&Bs[(wn * 64 + j * 16 + l) * 40 + quad * 8];
#pragma unroll
    for (int i = 0; i < 4; ++i)
#pragma unroll
      for (int j = 0; j < 4; ++j)
        acc[i][j] = __builtin_amdgcn_mfma_f32_16x16x32_bf16(af[i], bfr[j], acc[i][j], 0, 0, 0);
    __syncthreads();
  }
#pragma unroll
  for (int i = 0; i < 4; ++i) {
    int orow = m0 + wm * 64 + i * 16 + quad * 4;
#pragma unroll
    for (int j = 0; j < 4; ++j) {
      int ncol = n0 + wn * 64 + j * 16 + l;
#pragma unroll
      for (int r = 0; r < 4; ++r) {
        size_t oi = ((size_t)b * CDIM + orow + r) * NSEQ + ncol;
        float v = acc[i][j][r] + ldx(bout, orow + r, f32) + ldx(x, oi, f32);
        stx(out, oi, f32, v);
      }
    }
  }
}

extern "C" void kernel_launch(void* const* d_in, const int* in_sizes, int n_in,
                              void* d_out, int out_size, void* d_ws, size_t ws_size,
                              hipStream_t stream) {
  (void)in_sizes; (void)n_in; (void)out_size;
  const void* x    = d_in[0];
  const void* g    = d_in[1];
  const void* bln  = d_in[2];
  const void* wqkv = d_in[3];
  const void* wout = d_in[4];
  const void* bout = d_in[5];

  float* mean   = (float*)d_ws;                    // 8*8192
  float* rstd   = mean + BATCH * NSEQ;             // 8*8192
  float* ctxb   = rstd + BATCH * NSEQ;             // 65536
  float* sumexp = ctxb + BATCH * HEADS * DH * DH;  // 2048
  int*   mode   = (int*)(sumexp + BATCH * HEADS * DH);
  __hip_bfloat16* w2  = (__hip_bfloat16*)(mode + 64);            // 8*512*256
  __hip_bfloat16* w3  = w2 + (size_t)BATCH * CDIM * HID;         // 8*512*512
  __hip_bfloat16* wb  = w3 + (size_t)BATCH * CDIM * CDIM;        // 768*512
  __hip_bfloat16* xnt = wb + (size_t)O3 * CDIM;                  // 8*8192*512
  const size_t need = (size_t)((const char*)(xnt + (size_t)BATCH * NSEQ * CDIM) - (const char*)d_ws);

  hipMemsetAsync(ctxb, 0, (BATCH * HEADS * DH * DH + BATCH * HEADS * DH) * sizeof(float), stream);
  detect_kernel<<<1, 256, 0, stream>>>(x, mode);

  if (ws_size >= need) {
    ln_stats4_kernel<<<dim3(NSEQ / 128, BATCH), 256, 0, stream>>>(x, mode, mean, rstd);
    wconv_kernel<<<dim3((O3 * CDIM) / 2048), 256, 0, stream>>>(wqkv, mode, wb);
    xnormt_kernel<<<dim3(NSEQ / 128, CDIM / 128, BATCH), 256, 0, stream>>>(
        x, g, bln, mode, mean, rstd, xnt);
    kv_gemm3_kernel<<<dim3(NSEQ / 128, HEADS / 2, BATCH), 256, 0, stream>>>(
        wb, xnt, ctxb, sumexp);
    w2_build_kernel<<<dim3(CDIM, BATCH), 256, 0, stream>>>(wout, mode, ctxb, sumexp, w2);
    w3_gemm2_kernel<<<dim3(CDIM / 128, CDIM / 128, BATCH), 256, 0, stream>>>(w2, wb, w3);
    out_gemm3_kernel<<<dim3(NSEQ / 128, CDIM / 128, BATCH), 256, 0, stream>>>(
        x, w3, xnt, mode, bout, d_out);
  } else {
    ln_stats_kernel<<<dim3(NSEQ / 64, BATCH), 256, 0, stream>>>(x, mode, mean, rstd);
    kvctx_kernel<<<dim3(NSEQ / 128, HEADS / 2, BATCH), 256, 0, stream>>>(
        x, g, bln, wqkv, mode, mean, rstd, ctxb, sumexp);
    w2_build_kernel<<<dim3(CDIM, BATCH), 256, 0, stream>>>(wout, mode, ctxb, sumexp, w2);
    w3_gemm_kernel<<<dim3(CDIM / 128, CDIM / 128, BATCH), 256, 0, stream>>>(w2, wqkv, mode, w3);
    out_gemm_kernel<<<dim3(NSEQ / 128, CDIM / 128, BATCH), 256, 0, stream>>>(
        x, g, bln, w3, mode, mean, rstd, bout, d_out);
  }
}

// Round 3
// 589.055 us; speedup vs baseline: 2.1456x; 1.0077x over previous
//
#include <hip/hip_runtime.h>
#include <hip/hip_bf16.h>
#include <math.h>

#define HEADS 8
#define DH 32
#define BATCH 8
#define CDIM 512
#define NSEQ 8192
#define HID 256
#define O3 768
#define LNEPS 1e-5f
#define QSCALE 0.1767766952966369f  // 32^-0.5

typedef __bf16 bf16x8 __attribute__((ext_vector_type(8)));
typedef float f32x4 __attribute__((ext_vector_type(4)));
typedef unsigned short u16;
typedef u16 u16x4 __attribute__((ext_vector_type(4)));
typedef u16 u16x8 __attribute__((ext_vector_type(8)));

// async global->LDS 16B copy: LDS dest is wave-uniform base + lane*16 (m97 pattern)
__device__ __forceinline__ void gld_lds16(const void* g, void* l) {
  __builtin_amdgcn_global_load_lds(
      (const __attribute__((address_space(1))) unsigned int*)g,
      (__attribute__((address_space(3))) unsigned int*)l, 16, 0, 0);
}

// dual-dtype element load: mode==1 -> fp32 buffer, mode==0 -> bf16 buffer
__device__ __forceinline__ float ldx(const void* p, size_t i, bool f32) {
  if (f32) {
    float v = ((const float*)p)[i];
    return __builtin_isfinite(v) ? v : 0.f;
  }
  return __bfloat162float(((const __hip_bfloat16*)p)[i]);
}

__device__ __forceinline__ u16 b16(float v) {
  union { __hip_bfloat16 h; u16 u; } cv;
  cv.h = __float2bfloat16(v);
  return cv.u;
}

__device__ __forceinline__ float fb16(u16 u) {
  return __uint_as_float((unsigned)u << 16);
}

// stage 8 contiguous elements into LDS as bf16 (legacy path)
__device__ __forceinline__ void stage8(__hip_bfloat16* dst, const void* src, size_t idx, bool f32) {
  if (f32) {
    const float* s = (const float*)src + idx;
#pragma unroll
    for (int t = 0; t < 8; ++t) {
      float v = s[t];
      if (!__builtin_isfinite(v)) v = 0.f;
      dst[t] = __float2bfloat16(v);
    }
  } else {
    *(int4*)dst = *(const int4*)((const __hip_bfloat16*)src + idx);
  }
}

// dual-dtype store with finite scrub
__device__ __forceinline__ void stx(void* p, size_t i, bool f32, float v) {
  if (!__builtin_isfinite(v)) v = 0.f;
  if (f32) ((float*)p)[i] = v;
  else ((__hip_bfloat16*)p)[i] = __float2bfloat16(v);
}

// ---------------- kernel 0: dtype detector ----------------
__global__ __launch_bounds__(256) void detect_kernel(const void* __restrict__ x, int* __restrict__ mode) {
  __shared__ int cnt;
  if (threadIdx.x == 0) cnt = 0;
  __syncthreads();
  const __hip_bfloat16* p = (const __hip_bfloat16*)x;
  int c = 0;
  for (int i = threadIdx.x; i < 4096; i += 256) {
    float v = __bfloat162float(p[i]);
    if (!(v > -1.0e3f && v < 1.0e3f)) c++;
  }
  atomicAdd(&cnt, c);
  __syncthreads();
  if (threadIdx.x == 0) mode[0] = (cnt > 64) ? 1 : 0;
}

// ---------------- LN stats, float4-vectorized ----------------
__global__ __launch_bounds__(256) void ln_stats4_kernel(
    const void* __restrict__ x, const int* __restrict__ mode,
    float* __restrict__ mean, float* __restrict__ rstd) {
  const bool f32 = mode[0] != 0;
  const int b = blockIdx.y;
  const int n0 = blockIdx.x * 128;
  const int t = threadIdx.x;
  const int m = t & 31, cp = t >> 5;
  const int n4 = m * 4;
  const size_t base = (size_t)b * CDIM * NSEQ + n0 + n4;
  f32x4 s = {0.f, 0.f, 0.f, 0.f}, q = {0.f, 0.f, 0.f, 0.f};
  for (int c = cp * 64; c < cp * 64 + 64; ++c) {
    f32x4 v;
    if (f32) {
      v = *(const f32x4*)((const float*)x + base + (size_t)c * NSEQ);
#pragma unroll
      for (int j = 0; j < 4; ++j) if (!__builtin_isfinite(v[j])) v[j] = 0.f;
    } else {
      u16x4 h = *(const u16x4*)((const __hip_bfloat16*)x + base + (size_t)c * NSEQ);
#pragma unroll
      for (int j = 0; j < 4; ++j) v[j] = fb16(h[j]);
    }
    s += v;
    q += v * v;
  }
  __shared__ f32x4 sbS[8][32], sbQ[8][32];
  sbS[cp][m] = s; sbQ[cp][m] = q;
  __syncthreads();
  if (t < 32) {
    f32x4 S = sbS[0][t], Q = sbQ[0][t];
#pragma unroll
    for (int k = 1; k < 8; ++k) { S += sbS[k][t]; Q += sbQ[k][t]; }
    f32x4 M = S * (1.f / CDIM);
    f32x4 V = Q * (1.f / CDIM) - M * M;
#pragma unroll
    for (int j = 0; j < 4; ++j) {
      mean[b * NSEQ + n0 + t * 4 + j] = M[j];
      rstd[b * NSEQ + n0 + t * 4 + j] = rsqrtf(fmaxf(V[j], 0.f) + LNEPS);
    }
  }
}

// ---------------- wqkv -> bf16 once ----------------
__global__ __launch_bounds__(256) void wconv_kernel(
    const void* __restrict__ wqkv, const int* __restrict__ mode,
    __hip_bfloat16* __restrict__ wb) {
  const bool f32 = mode[0] != 0;
  const size_t i = ((size_t)blockIdx.x * 256 + threadIdx.x) * 8;
  if (f32) {
    f32x4 a = *(const f32x4*)((const float*)wqkv + i);
    f32x4 c = *(const f32x4*)((const float*)wqkv + i + 4);
    u16x8 o;
#pragma unroll
    for (int j = 0; j < 4; ++j) {
      float va = __builtin_isfinite(a[j]) ? a[j] : 0.f;
      float vc = __builtin_isfinite(c[j]) ? c[j] : 0.f;
      o[j] = b16(va);
      o[4 + j] = b16(vc);
    }
    *(u16x8*)&wb[i] = o;
  } else {
    *(int4*)&wb[i] = *(const int4*)((const __hip_bfloat16*)wqkv + i);
  }
}

// ---------------- xnormT[b][n][c] bf16 via LDS transpose ----------------
__global__ __launch_bounds__(256) void xnormt_kernel(
    const void* __restrict__ x, const void* __restrict__ g, const void* __restrict__ bln,
    const int* __restrict__ mode, const float* __restrict__ mean, const float* __restrict__ rstd,
    __hip_bfloat16* __restrict__ xnt) {
  const bool f32 = mode[0] != 0;
  const int b = blockIdx.z;
  const int c0 = blockIdx.y * 128;
  const int n0 = blockIdx.x * 128;
  __shared__ u16 tile[128 * 132];
  const int t = threadIdx.x;
  const int m = t & 31, rb = t >> 5;
  const int n4 = m * 4;
  const f32x4 mn = *(const f32x4*)&mean[b * NSEQ + n0 + n4];
  const f32x4 rs = *(const f32x4*)&rstd[b * NSEQ + n0 + n4];
#pragma unroll
  for (int it = 0; it < 16; ++it) {
    const int r = it * 8 + rb;
    const float gv = ldx(g, c0 + r, f32);
    const float bv = ldx(bln, c0 + r, f32);
    const size_t src = ((size_t)b * CDIM + c0 + r) * NSEQ + n0 + n4;
    f32x4 v;
    if (f32) {
      v = *(const f32x4*)((const float*)x + src);
#pragma unroll
      for (int j = 0; j < 4; ++j) if (!__builtin_isfinite(v[j])) v[j] = 0.f;
    } else {
      u16x4 h = *(const u16x4*)((const __hip_bfloat16*)x + src);
#pragma unroll
      for (int j = 0; j < 4; ++j) v[j] = fb16(h[j]);
    }
    u16x4 o;
#pragma unroll
    for (int j = 0; j < 4; ++j) o[j] = b16((v[j] - mn[j]) * rs[j] * gv + bv);
    *(u16x4*)&tile[r * 132 + n4] = o;
  }
  __syncthreads();
  const int n = t >> 1, ch = t & 1;
  __hip_bfloat16* dst = xnt + ((size_t)b * NSEQ + n0 + n) * CDIM + c0 + ch * 64;
#pragma unroll
  for (int i8 = 0; i8 < 8; ++i8) {
    u16x8 o;
#pragma unroll
    for (int k = 0; k < 8; ++k) o[k] = tile[(ch * 64 + i8 * 8 + k) * 132 + n];
    *(u16x8*)(dst + i8 * 8) = o;
  }
}

// ---------------- legacy kernel 1: LayerNorm stats ----------------
__global__ __launch_bounds__(256) void ln_stats_kernel(
    const void* __restrict__ x, const int* __restrict__ mode,
    float* __restrict__ mean, float* __restrict__ rstd) {
  const bool f32 = mode[0] != 0;
  int b = blockIdx.y;
  int nl = threadIdx.x & 63;
  int cp = threadIdx.x >> 6;
  int n = blockIdx.x * 64 + nl;
  size_t base = (size_t)b * CDIM * NSEQ + n;
  float s = 0.f, ss = 0.f;
  for (int c = cp * 128; c < cp * 128 + 128; ++c) {
    float v = ldx(x, base + (size_t)c * NSEQ, f32);
    s += v; ss += v * v;
  }
  __shared__ float sb[4][64], sb2[4][64];
  sb[cp][nl] = s; sb2[cp][nl] = ss;
  __syncthreads();
  if (cp == 0) {
    s = sb[0][nl] + sb[1][nl] + sb[2][nl] + sb[3][nl];
    ss = sb2[0][nl] + sb2[1][nl] + sb2[2][nl] + sb2[3][nl];
    float m = s * (1.f / CDIM);
    float var = ss * (1.f / CDIM) - m * m;
    mean[b * NSEQ + n] = m;
    rstd[b * NSEQ + n] = rsqrtf(fmaxf(var, 0.f) + LNEPS);
  }
}

// ---------------- K/V GEMM + exp + context, 2-phase double-buffered pipeline ----------------
__global__ __launch_bounds__(256) void kv_gemm4_kernel(
    const __hip_bfloat16* __restrict__ wb, const __hip_bfloat16* __restrict__ xnt,
    float* __restrict__ ctxb, float* __restrict__ sumexp) {
  const int b = blockIdx.z;
  const int p = blockIdx.y;
  const int n0 = blockIdx.x * 128;
  // union: dbuf As+Bs (2 x 16KB) / Ct (34KB)
  __shared__ __align__(16) char smem[128 * 136 * 2];
  __hip_bfloat16* Ct = (__hip_bfloat16*)smem;
  const int tid = threadIdx.x;
  const int lane = tid & 63;
  const int wv = tid >> 6;
  const int wm = wv >> 1, wn = wv & 1;
  const int quad = lane >> 4, l = lane & 15;
  f32x4 acc[4][4] = {};
  const __hip_bfloat16* xb = xnt + (size_t)b * NSEQ * CDIM;
  const int lr = lane >> 2, lc8 = (lane & 3) * 8;
  // prologue: stage k-tile 0 into buffer 0
  {
    __hip_bfloat16* As = (__hip_bfloat16*)smem;
    __hip_bfloat16* Bs = As + 128 * 32;
#pragma unroll
    for (int c = 0; c < 2; ++c) {
      int row = c * 64 + wv * 16 + lr;
      int srow = (row < 64) ? (256 + p * 64 + row) : (512 + p * 64 + row - 64);
      gld_lds16(&wb[(size_t)srow * CDIM + lc8], &As[(c * 64 + wv * 16) * 32]);
      gld_lds16(&xb[(size_t)(n0 + row) * CDIM + lc8], &Bs[(c * 64 + wv * 16) * 32]);
    }
  }
  __syncthreads();  // drains vmcnt(0): tile 0 ready
  int cur = 0;
  for (int t = 0; t < 16; ++t) {
    if (t < 15) {  // issue next tile's loads into the other buffer (latency hidden by compute)
      const int k0 = (t + 1) * 32;
      __hip_bfloat16* As = (__hip_bfloat16*)(smem + ((cur ^ 1) << 14));
      __hip_bfloat16* Bs = As + 128 * 32;
#pragma unroll
      for (int c = 0; c < 2; ++c) {
        int row = c * 64 + wv * 16 + lr;
        int srow = (row < 64) ? (256 + p * 64 + row) : (512 + p * 64 + row - 64);
        gld_lds16(&wb[(size_t)srow * CDIM + k0 + lc8], &As[(c * 64 + wv * 16) * 32]);
        gld_lds16(&xb[(size_t)(n0 + row) * CDIM + k0 + lc8], &Bs[(c * 64 + wv * 16) * 32]);
      }
    }
    {
      const __hip_bfloat16* As = (const __hip_bfloat16*)(smem + (cur << 14));
      const __hip_bfloat16* Bs = As + 128 * 32;
      bf16x8 af[4], bfr[4];
#pragma unroll
      for (int i = 0; i < 4; ++i)
        af[i] = *(const bf16x8*)&As[(wm * 64 + i * 16 + l) * 32 + quad * 8];
#pragma unroll
      for (int j = 0; j < 4; ++j)
        bfr[j] = *(const bf16x8*)&Bs[(wn * 64 + j * 16 + l) * 32 + quad * 8];
#pragma unroll
      for (int i = 0; i < 4; ++i)
#pragma unroll
        for (int j = 0; j < 4; ++j)
          acc[i][j] = __builtin_amdgcn_mfma_f32_16x16x32_bf16(af[i], bfr[j], acc[i][j], 0, 0, 0);
    }
    __syncthreads();  // one barrier/k-step: drains next-tile loads + guards buffer reuse
    cur ^= 1;
  }
  // epilogue: exp on K half (rows 0..63), clamp V half; write C tile to LDS
#pragma unroll
  for (int i = 0; i < 4; ++i) {
    int row = wm * 64 + i * 16 + quad * 4;
#pragma unroll
    for (int j = 0; j < 4; ++j) {
      int col = wn * 64 + j * 16 + l;
#pragma unroll
      for (int r = 0; r < 4; ++r) {
        float v = acc[i][j][r];
        if (wm == 0) v = expf(fminf(v, 20.f));
        else         v = fminf(fmaxf(v, -1.0e4f), 1.0e4f);
        Ct[(row + r) * 136 + col] = __float2bfloat16(v);
      }
    }
  }
  __syncthreads();
  const int mi = wm, ni = wn;
#pragma unroll
  for (int hh = 0; hh < 2; ++hh) {
    f32x4 ca = {};
#pragma unroll
    for (int ks = 0; ks < 4; ++ks) {
      bf16x8 ea = *(const bf16x8*)&Ct[(hh * 32 + mi * 16 + l) * 136 + ks * 32 + quad * 8];
      bf16x8 vb = *(const bf16x8*)&Ct[(64 + hh * 32 + ni * 16 + l) * 136 + ks * 32 + quad * 8];
      ca = __builtin_amdgcn_mfma_f32_16x16x32_bf16(ea, vb, ca, 0, 0, 0);
    }
    int h = p * 2 + hh;
    float* cp = ctxb + (size_t)(b * HEADS + h) * DH * DH;
#pragma unroll
    for (int r = 0; r < 4; ++r)
      atomicAdd(&cp[(mi * 16 + quad * 4 + r) * DH + ni * 16 + l], ca[r]);
  }
  if (tid < 64) {
    int hh = tid >> 5, d = tid & 31;
    float s = 0.f;
#pragma unroll 16
    for (int c = 0; c < 128; ++c) s += __bfloat162float(Ct[tid * 136 + c]);
    atomicAdd(&sumexp[(b * HEADS + p * 2 + hh) * DH + d], s);
  }
}

// ---------------- legacy kernel 2: fused K/V GEMM + exp + context ----------------
__global__ __launch_bounds__(256) void kvctx_kernel(
    const void* __restrict__ x, const void* __restrict__ g,
    const void* __restrict__ bln, const void* __restrict__ wqkv,
    const int* __restrict__ mode,
    const float* __restrict__ mean, const float* __restrict__ rstd,
    float* __restrict__ ctxb, float* __restrict__ sumexp) {
  const bool f32 = mode[0] != 0;
  const int b = blockIdx.z;
  const int p = blockIdx.y;
  const int n0 = blockIdx.x * 128;
  __shared__ __align__(16) __hip_bfloat16 As[128 * 32];
  __shared__ __align__(16) __hip_bfloat16 Bs[128 * 40];
  __shared__ __align__(16) __hip_bfloat16 Ct[128 * 136];
  const int tid = threadIdx.x;
  const int lane = tid & 63;
  const int wv = tid >> 6;
  const int wm = wv >> 1, wn = wv & 1;
  const int quad = lane >> 4, l = lane & 15;
  f32x4 acc[4][4] = {};
  const int nn = tid & 127;
  const int cb = tid >> 7;
  const float mn = mean[b * NSEQ + n0 + nn];
  const float rs = rstd[b * NSEQ + n0 + nn];
  const size_t xbase = (size_t)b * CDIM * NSEQ + n0 + nn;
  for (int k0 = 0; k0 < CDIM; k0 += 32) {
#pragma unroll
    for (int r = 0; r < 2; ++r) {
      int idx = (r * 256 + tid) * 8;
      int row = idx >> 5, col = idx & 31;
      int srow = (row < 64) ? (256 + p * 64 + row) : (512 + p * 64 + row - 64);
      stage8(&As[idx], wqkv, (size_t)srow * CDIM + k0 + col, f32);
    }
#pragma unroll
    for (int r = 0; r < 16; ++r) {
      int c = r * 2 + cb;
      float xv = ldx(x, xbase + (size_t)(k0 + c) * NSEQ, f32);
      float xn = (xv - mn) * rs;
      xn = xn * ldx(g, k0 + c, f32) + ldx(bln, k0 + c, f32);
      Bs[nn * 40 + c] = __float2bfloat16(xn);
    }
    __syncthreads();
    bf16x8 af[4], bfr[4];
#pragma unroll
    for (int i = 0; i < 4; ++i)
      af[i] = *(const bf16x8*)&As[(wm * 64 + i * 16 + l) * 32 + quad * 8];
#pragma unroll
    for (int j = 0; j < 4; ++j)
      bfr[j] = *(const bf16x8*)&Bs[(wn * 64 + j * 16 + l) * 40 + quad * 8];
#pragma unroll
    for (int i = 0; i < 4; ++i)
#pragma unroll
      for (int j = 0; j < 4; ++j)
        acc[i][j] = __builtin_amdgcn_mfma_f32_16x16x32_bf16(af[i], bfr[j], acc[i][j], 0, 0, 0);
    __syncthreads();
  }
#pragma unroll
  for (int i = 0; i < 4; ++i) {
    int row = wm * 64 + i * 16 + quad * 4;
#pragma unroll
    for (int j = 0; j < 4; ++j) {
      int col = wn * 64 + j * 16 + l;
#pragma unroll
      for (int r = 0; r < 4; ++r) {
        float v = acc[i][j][r];
        if (wm == 0) v = expf(fminf(v, 20.f));
        else         v = fminf(fmaxf(v, -1.0e4f), 1.0e4f);
        Ct[(row + r) * 136 + col] = __float2bfloat16(v);
      }
    }
  }
  __syncthreads();
  const int mi = wm, ni = wn;
#pragma unroll
  for (int hh = 0; hh < 2; ++hh) {
    f32x4 ca = {};
#pragma unroll
    for (int ks = 0; ks < 4; ++ks) {
      bf16x8 ea = *(const bf16x8*)&Ct[(hh * 32 + mi * 16 + l) * 136 + ks * 32 + quad * 8];
      bf16x8 vb = *(const bf16x8*)&Ct[(64 + hh * 32 + ni * 16 + l) * 136 + ks * 32 + quad * 8];
      ca = __builtin_amdgcn_mfma_f32_16x16x32_bf16(ea, vb, ca, 0, 0, 0);
    }
    int h = p * 2 + hh;
    float* cp = ctxb + (size_t)(b * HEADS + h) * DH * DH;
#pragma unroll
    for (int r = 0; r < 4; ++r)
      atomicAdd(&cp[(mi * 16 + quad * 4 + r) * DH + ni * 16 + l], ca[r]);
  }
  if (tid < 64) {
    int hh = tid >> 5, d = tid & 31;
    float s = 0.f;
#pragma unroll 16
    for (int c = 0; c < 128; ++c) s += __bfloat162float(Ct[tid * 136 + c]);
    atomicAdd(&sumexp[(b * HEADS + p * 2 + hh) * DH + d], s);
  }
}

// ---------------- kernel 3: W2 build (clamped) ----------------
__global__ __launch_bounds__(256) void w2_build_kernel(
    const void* __restrict__ wout, const int* __restrict__ mode,
    const float* __restrict__ ctxb, const float* __restrict__ sumexp,
    __hip_bfloat16* __restrict__ w2) {
  const bool f32 = mode[0] != 0;
  const int o = blockIdx.x;
  const int b = blockIdx.y;
  const int hd = threadIdx.x;
  const int h = hd >> 5, d = hd & 31;
  const float* cp = ctxb + ((size_t)(b * HEADS + h) * DH + d) * DH;
  float a = 0.f;
#pragma unroll
  for (int e = 0; e < DH; ++e) a += ldx(wout, (size_t)o * HID + h * DH + e, f32) * cp[e];
  float se = fmaxf(sumexp[(b * HEADS + h) * DH + d], 1e-30f);
  float v = a * QSCALE / se;
  v = fminf(fmaxf(v, -1.0e3f), 1.0e3f);
  w2[((size_t)b * CDIM + o) * HID + hd] = __float2bfloat16(v);
}

// ---------------- W3[b] = W2[b] (512x256) * Wq (256x512), bf16 sources ----------------
__global__ __launch_bounds__(256) void w3_gemm2_kernel(
    const __hip_bfloat16* __restrict__ w2, const __hip_bfloat16* __restrict__ wb,
    __hip_bfloat16* __restrict__ w3) {
  const int b = blockIdx.z;
  const int m0 = blockIdx.y * 128;
  const int n0 = blockIdx.x * 128;
  __shared__ __align__(16) __hip_bfloat16 As[128 * 40];
  __shared__ __align__(16) __hip_bfloat16 Bs[128 * 40];
  const int tid = threadIdx.x;
  const int lane = tid & 63;
  const int wv = tid >> 6;
  const int wm = wv >> 1, wn = wv & 1;
  const int quad = lane >> 4, l = lane & 15;
  f32x4 acc[4][4] = {};
  const int nn = tid & 127;
  const int cb = tid >> 7;
  const __hip_bfloat16* wa = w2 + (size_t)b * CDIM * HID;
  for (int k0 = 0; k0 < HID; k0 += 32) {
#pragma unroll
    for (int i = 0; i < 2; ++i) {
      int gid = tid + i * 256;
      int row = gid >> 2, c8 = (gid & 3) * 8;
      *(int4*)&As[row * 40 + c8] = *(const int4*)&wa[(size_t)(m0 + row) * HID + k0 + c8];
    }
#pragma unroll
    for (int r = 0; r < 16; ++r) {
      int hdl = r * 2 + cb;
      Bs[nn * 40 + hdl] = wb[(size_t)(k0 + hdl) * CDIM + n0 + nn];
    }
    __syncthreads();
    bf16x8 af[4], bfr[4];
#pragma unroll
    for (int i = 0; i < 4; ++i)
      af[i] = *(const bf16x8*)&As[(wm * 64 + i * 16 + l) * 40 + quad * 8];
#pragma unroll
    for (int j = 0; j < 4; ++j)
      bfr[j] = *(const bf16x8*)&Bs[(wn * 64 + j * 16 + l) * 40 + quad * 8];
#pragma unroll
    for (int i = 0; i < 4; ++i)
#pragma unroll
      for (int j = 0; j < 4; ++j)
        acc[i][j] = __builtin_amdgcn_mfma_f32_16x16x32_bf16(af[i], bfr[j], acc[i][j], 0, 0, 0);
    __syncthreads();
  }
#pragma unroll
  for (int i = 0; i < 4; ++i) {
    int orow = m0 + wm * 64 + i * 16 + quad * 4;
#pragma unroll
    for (int j = 0; j < 4; ++j) {
      int ncol = n0 + wn * 64 + j * 16 + l;
      __hip_bfloat16* op = w3 + ((size_t)b * CDIM + orow) * CDIM + ncol;
#pragma unroll
      for (int r = 0; r < 4; ++r) {
        float v = fminf(fmaxf(acc[i][j][r], -1.0e4f), 1.0e4f);
        op[(size_t)r * CDIM] = __float2bfloat16(v);
      }
    }
  }
}

// ---------------- legacy kernel 4: W3 GEMM ----------------
__global__ __launch_bounds__(256) void w3_gemm_kernel(
    const __hip_bfloat16* __restrict__ w2, const void* __restrict__ wqkv,
    const int* __restrict__ mode, __hip_bfloat16* __restrict__ w3) {
  const bool f32 = mode[0] != 0;
  const int b = blockIdx.z;
  const int m0 = blockIdx.y * 128;
  const int n0 = blockIdx.x * 128;
  __shared__ __align__(16) __hip_bfloat16 As[128 * 32];
  __shared__ __align__(16) __hip_bfloat16 Bs[128 * 40];
  const int tid = threadIdx.x;
  const int lane = tid & 63;
  const int wv = tid >> 6;
  const int wm = wv >> 1, wn = wv & 1;
  const int quad = lane >> 4, l = lane & 15;
  f32x4 acc[4][4] = {};
  const int nn = tid & 127;
  const int cb = tid >> 7;
  const __hip_bfloat16* wa = w2 + (size_t)b * CDIM * HID;
  for (int k0 = 0; k0 < HID; k0 += 32) {
#pragma unroll
    for (int r = 0; r < 2; ++r) {
      int idx = (r * 256 + tid) * 8;
      int row = idx >> 5, col = idx & 31;
      *(int4*)&As[idx] = *(const int4*)&wa[(size_t)(m0 + row) * HID + k0 + col];
    }
#pragma unroll
    for (int r = 0; r < 16; ++r) {
      int hdl = r * 2 + cb;
      Bs[nn * 40 + hdl] = __float2bfloat16(ldx(wqkv, (size_t)(k0 + hdl) * CDIM + n0 + nn, f32));
    }
    __syncthreads();
    bf16x8 af[4], bfr[4];
#pragma unroll
    for (int i = 0; i < 4; ++i)
      af[i] = *(const bf16x8*)&As[(wm * 64 + i * 16 + l) * 32 + quad * 8];
#pragma unroll
    for (int j = 0; j < 4; ++j)
      bfr[j] = *(const bf16x8*)&Bs[(wn * 64 + j * 16 + l) * 40 + quad * 8];
#pragma unroll
    for (int i = 0; i < 4; ++i)
#pragma unroll
      for (int j = 0; j < 4; ++j)
        acc[i][j] = __builtin_amdgcn_mfma_f32_16x16x32_bf16(af[i], bfr[j], acc[i][j], 0, 0, 0);
    __syncthreads();
  }
#pragma unroll
  for (int i = 0; i < 4; ++i) {
    int orow = m0 + wm * 64 + i * 16 + quad * 4;
#pragma unroll
    for (int j = 0; j < 4; ++j) {
      int ncol = n0 + wn * 64 + j * 16 + l;
      __hip_bfloat16* op = w3 + ((size_t)b * CDIM + orow) * CDIM + ncol;
#pragma unroll
      for (int r = 0; r < 4; ++r) {
        float v = fminf(fmaxf(acc[i][j][r], -1.0e4f), 1.0e4f);
        op[(size_t)r * CDIM] = __float2bfloat16(v);
      }
    }
  }
}

// ---------------- out = W3[b] * xnormT + b_out + x, 2-phase double-buffered pipeline ----------------
__global__ __launch_bounds__(256) void out_gemm4_kernel(
    const void* __restrict__ x, const __hip_bfloat16* __restrict__ w3,
    const __hip_bfloat16* __restrict__ xnt, const int* __restrict__ mode,
    const void* __restrict__ bout, void* __restrict__ out) {
  const bool f32 = mode[0] != 0;
  const int b = blockIdx.z;
  const int m0 = blockIdx.y * 128;
  const int n0 = blockIdx.x * 128;
  __shared__ __align__(16) char smem[2 * 128 * 64 * 2];  // 2 buffers x (As 8KB + Bs 8KB)
  const int tid = threadIdx.x;
  const int lane = tid & 63;
  const int wv = tid >> 6;
  const int wm = wv >> 1, wn = wv & 1;
  const int quad = lane >> 4, l = lane & 15;
  f32x4 acc[4][4] = {};
  const __hip_bfloat16* wa = w3 + (size_t)b * CDIM * CDIM;
  const __hip_bfloat16* xb = xnt + (size_t)b * NSEQ * CDIM;
  const int lr = lane >> 2, lc8 = (lane & 3) * 8;
  // prologue: stage k-tile 0 into buffer 0
  {
    __hip_bfloat16* As = (__hip_bfloat16*)smem;
    __hip_bfloat16* Bs = As + 128 * 32;
#pragma unroll
    for (int c = 0; c < 2; ++c) {
      int row = c * 64 + wv * 16 + lr;
      gld_lds16(&wa[(size_t)(m0 + row) * CDIM + lc8], &As[(c * 64 + wv * 16) * 32]);
      gld_lds16(&xb[(size_t)(n0 + row) * CDIM + lc8], &Bs[(c * 64 + wv * 16) * 32]);
    }
  }
  __syncthreads();
  int cur = 0;
  for (int t = 0; t < 16; ++t) {
    if (t < 15) {
      const int k0 = (t + 1) * 32;
      __hip_bfloat16* As = (__hip_bfloat16*)(smem + ((cur ^ 1) << 14));
      __hip_bfloat16* Bs = As + 128 * 32;
#pragma unroll
      for (int c = 0; c < 2; ++c) {
        int row = c * 64 + wv * 16 + lr;
        gld_lds16(&wa[(size_t)(m0 + row) * CDIM + k0 + lc8], &As[(c * 64 + wv * 16) * 32]);
        gld_lds16(&xb[(size_t)(n0 + row) * CDIM + k0 + lc8], &Bs[(c * 64 + wv * 16) * 32]);
      }
    }
    {
      const __hip_bfloat16* As = (const __hip_bfloat16*)(smem + (cur << 14));
      const __hip_bfloat16* Bs = As + 128 * 32;
      bf16x8 af[4], bfr[4];
#pragma unroll
      for (int i = 0; i < 4; ++i)
        af[i] = *(const bf16x8*)&As[(wm * 64 + i * 16 + l) * 32 + quad * 8];
#pragma unroll
      for (int j = 0; j < 4; ++j)
        bfr[j] = *(const bf16x8*)&Bs[(wn * 64 + j * 16 + l) * 32 + quad * 8];
#pragma unroll
      for (int i = 0; i < 4; ++i)
#pragma unroll
        for (int j = 0; j < 4; ++j)
          acc[i][j] = __builtin_amdgcn_mfma_f32_16x16x32_bf16(af[i], bfr[j], acc[i][j], 0, 0, 0);
    }
    __syncthreads();
    cur ^= 1;
  }
#pragma unroll
  for (int i = 0; i < 4; ++i) {
    int orow = m0 + wm * 64 + i * 16 + quad * 4;
#pragma unroll
    for (int j = 0; j < 4; ++j) {
      int ncol = n0 + wn * 64 + j * 16 + l;
#pragma unroll
      for (int r = 0; r < 4; ++r) {
        size_t oi = ((size_t)b * CDIM + orow + r) * NSEQ + ncol;
        float v = acc[i][j][r] + ldx(bout, orow + r, f32) + ldx(x, oi, f32);
        stx(out, oi, f32, v);
      }
    }
  }
}

// ---------------- legacy kernel 5: out GEMM ----------------
__global__ __launch_bounds__(256) void out_gemm_kernel(
    const void* __restrict__ x, const void* __restrict__ g,
    const void* __restrict__ bln, const __hip_bfloat16* __restrict__ w3,
    const int* __restrict__ mode,
    const float* __restrict__ mean, const float* __restrict__ rstd,
    const void* __restrict__ bout, void* __restrict__ out) {
  const bool f32 = mode[0] != 0;
  const int b = blockIdx.z;
  const int m0 = blockIdx.y * 128;
  const int n0 = blockIdx.x * 128;
  __shared__ __align__(16) __hip_bfloat16 As[128 * 32];
  __shared__ __align__(16) __hip_bfloat16 Bs[128 * 40];
  const int tid = threadIdx.x;
  const int lane = tid & 63;
  const int wv = tid >> 6;
  const int wm = wv >> 1, wn = wv & 1;
  const int quad = lane >> 4, l = lane & 15;
  f32x4 acc[4][4] = {};
  const int nn = tid & 127;
  const int cb = tid >> 7;
  const float mn = mean[b * NSEQ + n0 + nn];
  const float rs = rstd[b * NSEQ + n0 + nn];
  const size_t xbase = (size_t)b * CDIM * NSEQ + n0 + nn;
  const __hip_bfloat16* wa = w3 + (size_t)b * CDIM * CDIM;
  for (int k0 = 0; k0 < CDIM; k0 += 32) {
#pragma unroll
    for (int r = 0; r < 2; ++r) {
      int idx = (r * 256 + tid) * 8;
      int row = idx >> 5, col = idx & 31;
      *(int4*)&As[idx] = *(const int4*)&wa[(size_t)(m0 + row) * CDIM + k0 + col];
    }
#pragma unroll
    for (int r = 0; r < 16; ++r) {
      int c = r * 2 + cb;
      float xv = ldx(x, xbase + (size_t)(k0 + c) * NSEQ, f32);
      float xn = (xv - mn) * rs;
      xn = xn * ldx(g, k0 + c, f32) + ldx(bln, k0 + c, f32);
      Bs[nn * 40 + c] = __float2bfloat16(xn);
    }
    __syncthreads();
    bf16x8 af[4], bfr[4];
#pragma unroll
    for (int i = 0; i < 4; ++i)
      af[i] = *(const bf16x8*)&As[(wm * 64 + i * 16 + l) * 32 + quad * 8];
#pragma unroll
    for (int j = 0; j < 4; ++j)
      bfr[j] = *(const bf16x8*)&Bs[(wn * 64 + j * 16 + l) * 40 + quad * 8];
#pragma unroll
    for (int i = 0; i < 4; ++i)
#pragma unroll
      for (int j = 0; j < 4; ++j)
        acc[i][j] = __builtin_amdgcn_mfma_f32_16x16x32_bf16(af[i], bfr[j], acc[i][j], 0, 0, 0);
    __syncthreads();
  }
#pragma unroll
  for (int i = 0; i < 4; ++i) {
    int orow = m0 + wm * 64 + i * 16 + quad * 4;
#pragma unroll
    for (int j = 0; j < 4; ++j) {
      int ncol = n0 + wn * 64 + j * 16 + l;
#pragma unroll
      for (int r = 0; r < 4; ++r) {
        size_t oi = ((size_t)b * CDIM + orow + r) * NSEQ + ncol;
        float v = acc[i][j][r] + ldx(bout, orow + r, f32) + ldx(x, oi, f32);
        stx(out, oi, f32, v);
      }
    }
  }
}

extern "C" void kernel_launch(void* const* d_in, const int* in_sizes, int n_in,
                              void* d_out, int out_size, void* d_ws, size_t ws_size,
                              hipStream_t stream) {
  (void)in_sizes; (void)n_in; (void)out_size;
  const void* x    = d_in[0];
  const void* g    = d_in[1];
  const void* bln  = d_in[2];
  const void* wqkv = d_in[3];
  const void* wout = d_in[4];
  const void* bout = d_in[5];

  float* mean   = (float*)d_ws;                    // 8*8192
  float* rstd   = mean + BATCH * NSEQ;             // 8*8192
  float* ctxb   = rstd + BATCH * NSEQ;             // 65536
  float* sumexp = ctxb + BATCH * HEADS * DH * DH;  // 2048
  int*   mode   = (int*)(sumexp + BATCH * HEADS * DH);
  __hip_bfloat16* w2  = (__hip_bfloat16*)(mode + 64);            // 8*512*256
  __hip_bfloat16* w3  = w2 + (size_t)BATCH * CDIM * HID;         // 8*512*512
  __hip_bfloat16* wb  = w3 + (size_t)BATCH * CDIM * CDIM;        // 768*512
  __hip_bfloat16* xnt = wb + (size_t)O3 * CDIM;                  // 8*8192*512
  const size_t need = (size_t)((const char*)(xnt + (size_t)BATCH * NSEQ * CDIM) - (const char*)d_ws);

  hipMemsetAsync(ctxb, 0, (BATCH * HEADS * DH * DH + BATCH * HEADS * DH) * sizeof(float), stream);
  detect_kernel<<<1, 256, 0, stream>>>(x, mode);

  if (ws_size >= need) {
    ln_stats4_kernel<<<dim3(NSEQ / 128, BATCH), 256, 0, stream>>>(x, mode, mean, rstd);
    wconv_kernel<<<dim3((O3 * CDIM) / 2048), 256, 0, stream>>>(wqkv, mode, wb);
    xnormt_kernel<<<dim3(NSEQ / 128, CDIM / 128, BATCH), 256, 0, stream>>>(
        x, g, bln, mode, mean, rstd, xnt);
    kv_gemm4_kernel<<<dim3(NSEQ / 128, HEADS / 2, BATCH), 256, 0, stream>>>(
        wb, xnt, ctxb, sumexp);
    w2_build_kernel<<<dim3(CDIM, BATCH), 256, 0, stream>>>(wout, mode, ctxb, sumexp, w2);
    w3_gemm2_kernel<<<dim3(CDIM / 128, CDIM / 128, BATCH), 256, 0, stream>>>(w2, wb, w3);
    out_gemm4_kernel<<<dim3(NSEQ / 128, CDIM / 128, BATCH), 256, 0, stream>>>(
        x, w3, xnt, mode, bout, d_out);
  } else {
    ln_stats_kernel<<<dim3(NSEQ / 64, BATCH), 256, 0, stream>>>(x, mode, mean, rstd);
    kvctx_kernel<<<dim3(NSEQ / 128, HEADS / 2, BATCH), 256, 0, stream>>>(
        x, g, bln, wqkv, mode, mean, rstd, ctxb, sumexp);
    w2_build_kernel<<<dim3(CDIM, BATCH), 256, 0, stream>>>(wout, mode, ctxb, sumexp, w2);
    w3_gemm_kernel<<<dim3(CDIM / 128, CDIM / 128, BATCH), 256, 0, stream>>>(w2, wqkv, mode, w3);
    out_gemm_kernel<<<dim3(NSEQ / 128, CDIM / 128, BATCH), 256, 0, stream>>>(
        x, g, bln, w3, mode, mean, rstd, bout, d_out);
  }
}

// Round 4
// 576.193 us; speedup vs baseline: 2.1935x; 1.0223x over previous
//
#include <hip/hip_runtime.h>
#include <hip/hip_bf16.h>
#include <math.h>

#define HEADS 8
#define DH 32
#define BATCH 8
#define CDIM 512
#define NSEQ 8192
#define HID 256
#define O3 768
#define LNEPS 1e-5f
#define QSCALE 0.1767766952966369f  // 32^-0.5

typedef __bf16 bf16x8 __attribute__((ext_vector_type(8)));
typedef float f32x4 __attribute__((ext_vector_type(4)));
typedef unsigned short u16;
typedef u16 u16x4 __attribute__((ext_vector_type(4)));
typedef u16 u16x8 __attribute__((ext_vector_type(8)));

// async global->LDS 16B copy: LDS dest is wave-uniform base + lane*16 (m97 pattern)
__device__ __forceinline__ void gld_lds16(const void* g, void* l) {
  __builtin_amdgcn_global_load_lds(
      (const __attribute__((address_space(1))) unsigned int*)g,
      (__attribute__((address_space(3))) unsigned int*)l, 16, 0, 0);
}

// dual-dtype element load: mode==1 -> fp32 buffer, mode==0 -> bf16 buffer
__device__ __forceinline__ float ldx(const void* p, size_t i, bool f32) {
  if (f32) {
    float v = ((const float*)p)[i];
    return __builtin_isfinite(v) ? v : 0.f;
  }
  return __bfloat162float(((const __hip_bfloat16*)p)[i]);
}

__device__ __forceinline__ u16 b16(float v) {
  union { __hip_bfloat16 h; u16 u; } cv;
  cv.h = __float2bfloat16(v);
  return cv.u;
}

__device__ __forceinline__ float fb16(u16 u) {
  return __uint_as_float((unsigned)u << 16);
}

// stage 8 contiguous elements into LDS as bf16 (legacy path)
__device__ __forceinline__ void stage8(__hip_bfloat16* dst, const void* src, size_t idx, bool f32) {
  if (f32) {
    const float* s = (const float*)src + idx;
#pragma unroll
    for (int t = 0; t < 8; ++t) {
      float v = s[t];
      if (!__builtin_isfinite(v)) v = 0.f;
      dst[t] = __float2bfloat16(v);
    }
  } else {
    *(int4*)dst = *(const int4*)((const __hip_bfloat16*)src + idx);
  }
}

// dual-dtype store with finite scrub
__device__ __forceinline__ void stx(void* p, size_t i, bool f32, float v) {
  if (!__builtin_isfinite(v)) v = 0.f;
  if (f32) ((float*)p)[i] = v;
  else ((__hip_bfloat16*)p)[i] = __float2bfloat16(v);
}

// ---------------- kernel 0: dtype detector ----------------
__global__ __launch_bounds__(256) void detect_kernel(const void* __restrict__ x, int* __restrict__ mode) {
  __shared__ int cnt;
  if (threadIdx.x == 0) cnt = 0;
  __syncthreads();
  const __hip_bfloat16* p = (const __hip_bfloat16*)x;
  int c = 0;
  for (int i = threadIdx.x; i < 4096; i += 256) {
    float v = __bfloat162float(p[i]);
    if (!(v > -1.0e3f && v < 1.0e3f)) c++;
  }
  atomicAdd(&cnt, c);
  __syncthreads();
  if (threadIdx.x == 0) mode[0] = (cnt > 64) ? 1 : 0;
}

// ---------------- LN stats, float4-vectorized ----------------
__global__ __launch_bounds__(256) void ln_stats4_kernel(
    const void* __restrict__ x, const int* __restrict__ mode,
    float* __restrict__ mean, float* __restrict__ rstd) {
  const bool f32 = mode[0] != 0;
  const int b = blockIdx.y;
  const int n0 = blockIdx.x * 128;
  const int t = threadIdx.x;
  const int m = t & 31, cp = t >> 5;
  const int n4 = m * 4;
  const size_t base = (size_t)b * CDIM * NSEQ + n0 + n4;
  f32x4 s = {0.f, 0.f, 0.f, 0.f}, q = {0.f, 0.f, 0.f, 0.f};
  for (int c = cp * 64; c < cp * 64 + 64; ++c) {
    f32x4 v;
    if (f32) {
      v = *(const f32x4*)((const float*)x + base + (size_t)c * NSEQ);
#pragma unroll
      for (int j = 0; j < 4; ++j) if (!__builtin_isfinite(v[j])) v[j] = 0.f;
    } else {
      u16x4 h = *(const u16x4*)((const __hip_bfloat16*)x + base + (size_t)c * NSEQ);
#pragma unroll
      for (int j = 0; j < 4; ++j) v[j] = fb16(h[j]);
    }
    s += v;
    q += v * v;
  }
  __shared__ f32x4 sbS[8][32], sbQ[8][32];
  sbS[cp][m] = s; sbQ[cp][m] = q;
  __syncthreads();
  if (t < 32) {
    f32x4 S = sbS[0][t], Q = sbQ[0][t];
#pragma unroll
    for (int k = 1; k < 8; ++k) { S += sbS[k][t]; Q += sbQ[k][t]; }
    f32x4 M = S * (1.f / CDIM);
    f32x4 V = Q * (1.f / CDIM) - M * M;
#pragma unroll
    for (int j = 0; j < 4; ++j) {
      mean[b * NSEQ + n0 + t * 4 + j] = M[j];
      rstd[b * NSEQ + n0 + t * 4 + j] = rsqrtf(fmaxf(V[j], 0.f) + LNEPS);
    }
  }
}

// ---------------- wqkv -> bf16 once ----------------
__global__ __launch_bounds__(256) void wconv_kernel(
    const void* __restrict__ wqkv, const int* __restrict__ mode,
    __hip_bfloat16* __restrict__ wb) {
  const bool f32 = mode[0] != 0;
  const size_t i = ((size_t)blockIdx.x * 256 + threadIdx.x) * 8;
  if (f32) {
    f32x4 a = *(const f32x4*)((const float*)wqkv + i);
    f32x4 c = *(const f32x4*)((const float*)wqkv + i + 4);
    u16x8 o;
#pragma unroll
    for (int j = 0; j < 4; ++j) {
      float va = __builtin_isfinite(a[j]) ? a[j] : 0.f;
      float vc = __builtin_isfinite(c[j]) ? c[j] : 0.f;
      o[j] = b16(va);
      o[4 + j] = b16(vc);
    }
    *(u16x8*)&wb[i] = o;
  } else {
    *(int4*)&wb[i] = *(const int4*)((const __hip_bfloat16*)wqkv + i);
  }
}

// ---------------- xnormT[b][n][c] bf16 via LDS transpose ----------------
__global__ __launch_bounds__(256) void xnormt_kernel(
    const void* __restrict__ x, const void* __restrict__ g, const void* __restrict__ bln,
    const int* __restrict__ mode, const float* __restrict__ mean, const float* __restrict__ rstd,
    __hip_bfloat16* __restrict__ xnt) {
  const bool f32 = mode[0] != 0;
  const int b = blockIdx.z;
  const int c0 = blockIdx.y * 128;
  const int n0 = blockIdx.x * 128;
  __shared__ u16 tile[128 * 132];
  const int t = threadIdx.x;
  const int m = t & 31, rb = t >> 5;
  const int n4 = m * 4;
  const f32x4 mn = *(const f32x4*)&mean[b * NSEQ + n0 + n4];
  const f32x4 rs = *(const f32x4*)&rstd[b * NSEQ + n0 + n4];
#pragma unroll
  for (int it = 0; it < 16; ++it) {
    const int r = it * 8 + rb;
    const float gv = ldx(g, c0 + r, f32);
    const float bv = ldx(bln, c0 + r, f32);
    const size_t src = ((size_t)b * CDIM + c0 + r) * NSEQ + n0 + n4;
    f32x4 v;
    if (f32) {
      v = *(const f32x4*)((const float*)x + src);
#pragma unroll
      for (int j = 0; j < 4; ++j) if (!__builtin_isfinite(v[j])) v[j] = 0.f;
    } else {
      u16x4 h = *(const u16x4*)((const __hip_bfloat16*)x + src);
#pragma unroll
      for (int j = 0; j < 4; ++j) v[j] = fb16(h[j]);
    }
    u16x4 o;
#pragma unroll
    for (int j = 0; j < 4; ++j) o[j] = b16((v[j] - mn[j]) * rs[j] * gv + bv);
    *(u16x4*)&tile[r * 132 + n4] = o;
  }
  __syncthreads();
  const int n = t >> 1, ch = t & 1;
  __hip_bfloat16* dst = xnt + ((size_t)b * NSEQ + n0 + n) * CDIM + c0 + ch * 64;
#pragma unroll
  for (int i8 = 0; i8 < 8; ++i8) {
    u16x8 o;
#pragma unroll
    for (int k = 0; k < 8; ++k) o[k] = tile[(ch * 64 + i8 * 8 + k) * 132 + n];
    *(u16x8*)(dst + i8 * 8) = o;
  }
}

// ---------------- legacy kernel 1: LayerNorm stats ----------------
__global__ __launch_bounds__(256) void ln_stats_kernel(
    const void* __restrict__ x, const int* __restrict__ mode,
    float* __restrict__ mean, float* __restrict__ rstd) {
  const bool f32 = mode[0] != 0;
  int b = blockIdx.y;
  int nl = threadIdx.x & 63;
  int cp = threadIdx.x >> 6;
  int n = blockIdx.x * 64 + nl;
  size_t base = (size_t)b * CDIM * NSEQ + n;
  float s = 0.f, ss = 0.f;
  for (int c = cp * 128; c < cp * 128 + 128; ++c) {
    float v = ldx(x, base + (size_t)c * NSEQ, f32);
    s += v; ss += v * v;
  }
  __shared__ float sb[4][64], sb2[4][64];
  sb[cp][nl] = s; sb2[cp][nl] = ss;
  __syncthreads();
  if (cp == 0) {
    s = sb[0][nl] + sb[1][nl] + sb[2][nl] + sb[3][nl];
    ss = sb2[0][nl] + sb2[1][nl] + sb2[2][nl] + sb2[3][nl];
    float m = s * (1.f / CDIM);
    float var = ss * (1.f / CDIM) - m * m;
    mean[b * NSEQ + n] = m;
    rstd[b * NSEQ + n] = rsqrtf(fmaxf(var, 0.f) + LNEPS);
  }
}

// ---------------- K/V GEMM + exp + context: 3-buffer counted-vmcnt pipeline ----------------
// LDS swizzle (rule 21): linear gld_lds dest; source chunk c4^(r16&3); same XOR on read.
__global__ __launch_bounds__(256) void kv_gemm5_kernel(
    const __hip_bfloat16* __restrict__ wb, const __hip_bfloat16* __restrict__ xnt,
    float* __restrict__ ctxb, float* __restrict__ sumexp) {
  const int b = blockIdx.z;
  const int p = blockIdx.y;
  const int n0 = blockIdx.x * 128;
  // union: 3 x 16KB (As 8KB + Bs 8KB) pipeline buffers / Ct (34KB)
  __shared__ __align__(16) char smem[49152];
  __hip_bfloat16* Ct = (__hip_bfloat16*)smem;
  const int tid = threadIdx.x;
  const int lane = tid & 63;
  const int wv = tid >> 6;
  const int wm = wv >> 1, wn = wv & 1;
  const int quad = lane >> 4, l = lane & 15;
  f32x4 acc[4][4] = {};
  const __hip_bfloat16* xb = xnt + (size_t)b * NSEQ * CDIM;
  // stage geometry: lane covers 16B chunk c4 of row r16 within a 16-row group
  const int r16 = lane >> 2;
  const int cs8 = ((lane & 3) ^ (r16 & 3)) * 8;  // swizzled source element offset
  const int rowA = wv * 16 + r16;                 // 0..63
  // read-side swizzled chunk offset (ra&3 == l&3 since row bases are mult of 4)
  const int cq = (quad ^ (l & 3)) * 8;

#define KV_STAGE(bufidx, k0) do {                                              \
    __hip_bfloat16* As_ = (__hip_bfloat16*)(smem + (bufidx) * 16384);          \
    __hip_bfloat16* Bs_ = As_ + 128 * 32;                                      \
    gld_lds16(&wb[(size_t)(256 + p * 64 + rowA) * CDIM + (k0) + cs8],          \
              &As_[(wv * 16) * 32]);                                           \
    gld_lds16(&wb[(size_t)(512 + p * 64 + rowA) * CDIM + (k0) + cs8],          \
              &As_[(64 + wv * 16) * 32]);                                      \
    gld_lds16(&xb[(size_t)(n0 + rowA) * CDIM + (k0) + cs8],                    \
              &Bs_[(wv * 16) * 32]);                                           \
    gld_lds16(&xb[(size_t)(n0 + 64 + rowA) * CDIM + (k0) + cs8],               \
              &Bs_[(64 + wv * 16) * 32]);                                      \
  } while (0)

  KV_STAGE(0, 0);
  KV_STAGE(1, 32);
  for (int t = 0; t < 16; ++t) {
    if (t < 15) asm volatile("s_waitcnt vmcnt(4)" ::: "memory");
    else        asm volatile("s_waitcnt vmcnt(0)" ::: "memory");
    __builtin_amdgcn_s_barrier();
    __builtin_amdgcn_sched_barrier(0);
    if (t + 2 < 16) {
      int bi = (t + 2) % 3;
      KV_STAGE(bi, (t + 2) * 32);
    }
    const __hip_bfloat16* As = (const __hip_bfloat16*)(smem + (t % 3) * 16384);
    const __hip_bfloat16* Bs = As + 128 * 32;
    bf16x8 af[4], bfr[4];
#pragma unroll
    for (int i = 0; i < 4; ++i)
      af[i] = *(const bf16x8*)&As[(wm * 64 + i * 16 + l) * 32 + cq];
#pragma unroll
    for (int j = 0; j < 4; ++j)
      bfr[j] = *(const bf16x8*)&Bs[(wn * 64 + j * 16 + l) * 32 + cq];
#pragma unroll
    for (int i = 0; i < 4; ++i)
#pragma unroll
      for (int j = 0; j < 4; ++j)
        acc[i][j] = __builtin_amdgcn_mfma_f32_16x16x32_bf16(af[i], bfr[j], acc[i][j], 0, 0, 0);
  }
#undef KV_STAGE
  __syncthreads();  // all ds_reads done; safe to reuse smem as Ct
  // epilogue: exp on K half (rows 0..63), clamp V half; write C tile to LDS
#pragma unroll
  for (int i = 0; i < 4; ++i) {
    int row = wm * 64 + i * 16 + quad * 4;
#pragma unroll
    for (int j = 0; j < 4; ++j) {
      int col = wn * 64 + j * 16 + l;
#pragma unroll
      for (int r = 0; r < 4; ++r) {
        float v = acc[i][j][r];
        if (wm == 0) v = expf(fminf(v, 20.f));
        else         v = fminf(fmaxf(v, -1.0e4f), 1.0e4f);
        Ct[(row + r) * 136 + col] = __float2bfloat16(v);
      }
    }
  }
  __syncthreads();
  const int mi = wm, ni = wn;
#pragma unroll
  for (int hh = 0; hh < 2; ++hh) {
    f32x4 ca = {};
#pragma unroll
    for (int ks = 0; ks < 4; ++ks) {
      bf16x8 ea = *(const bf16x8*)&Ct[(hh * 32 + mi * 16 + l) * 136 + ks * 32 + quad * 8];
      bf16x8 vb = *(const bf16x8*)&Ct[(64 + hh * 32 + ni * 16 + l) * 136 + ks * 32 + quad * 8];
      ca = __builtin_amdgcn_mfma_f32_16x16x32_bf16(ea, vb, ca, 0, 0, 0);
    }
    int h = p * 2 + hh;
    float* cp = ctxb + (size_t)(b * HEADS + h) * DH * DH;
#pragma unroll
    for (int r = 0; r < 4; ++r)
      atomicAdd(&cp[(mi * 16 + quad * 4 + r) * DH + ni * 16 + l], ca[r]);
  }
  if (tid < 64) {
    int hh = tid >> 5, d = tid & 31;
    float s = 0.f;
#pragma unroll 16
    for (int c = 0; c < 128; ++c) s += __bfloat162float(Ct[tid * 136 + c]);
    atomicAdd(&sumexp[(b * HEADS + p * 2 + hh) * DH + d], s);
  }
}

// ---------------- legacy kernel 2: fused K/V GEMM + exp + context ----------------
__global__ __launch_bounds__(256) void kvctx_kernel(
    const void* __restrict__ x, const void* __restrict__ g,
    const void* __restrict__ bln, const void* __restrict__ wqkv,
    const int* __restrict__ mode,
    const float* __restrict__ mean, const float* __restrict__ rstd,
    float* __restrict__ ctxb, float* __restrict__ sumexp) {
  const bool f32 = mode[0] != 0;
  const int b = blockIdx.z;
  const int p = blockIdx.y;
  const int n0 = blockIdx.x * 128;
  __shared__ __align__(16) __hip_bfloat16 As[128 * 32];
  __shared__ __align__(16) __hip_bfloat16 Bs[128 * 40];
  __shared__ __align__(16) __hip_bfloat16 Ct[128 * 136];
  const int tid = threadIdx.x;
  const int lane = tid & 63;
  const int wv = tid >> 6;
  const int wm = wv >> 1, wn = wv & 1;
  const int quad = lane >> 4, l = lane & 15;
  f32x4 acc[4][4] = {};
  const int nn = tid & 127;
  const int cb = tid >> 7;
  const float mn = mean[b * NSEQ + n0 + nn];
  const float rs = rstd[b * NSEQ + n0 + nn];
  const size_t xbase = (size_t)b * CDIM * NSEQ + n0 + nn;
  for (int k0 = 0; k0 < CDIM; k0 += 32) {
#pragma unroll
    for (int r = 0; r < 2; ++r) {
      int idx = (r * 256 + tid) * 8;
      int row = idx >> 5, col = idx & 31;
      int srow = (row < 64) ? (256 + p * 64 + row) : (512 + p * 64 + row - 64);
      stage8(&As[idx], wqkv, (size_t)srow * CDIM + k0 + col, f32);
    }
#pragma unroll
    for (int r = 0; r < 16; ++r) {
      int c = r * 2 + cb;
      float xv = ldx(x, xbase + (size_t)(k0 + c) * NSEQ, f32);
      float xn = (xv - mn) * rs;
      xn = xn * ldx(g, k0 + c, f32) + ldx(bln, k0 + c, f32);
      Bs[nn * 40 + c] = __float2bfloat16(xn);
    }
    __syncthreads();
    bf16x8 af[4], bfr[4];
#pragma unroll
    for (int i = 0; i < 4; ++i)
      af[i] = *(const bf16x8*)&As[(wm * 64 + i * 16 + l) * 32 + quad * 8];
#pragma unroll
    for (int j = 0; j < 4; ++j)
      bfr[j] = *(const bf16x8*)&Bs[(wn * 64 + j * 16 + l) * 40 + quad * 8];
#pragma unroll
    for (int i = 0; i < 4; ++i)
#pragma unroll
      for (int j = 0; j < 4; ++j)
        acc[i][j] = __builtin_amdgcn_mfma_f32_16x16x32_bf16(af[i], bfr[j], acc[i][j], 0, 0, 0);
    __syncthreads();
  }
#pragma unroll
  for (int i = 0; i < 4; ++i) {
    int row = wm * 64 + i * 16 + quad * 4;
#pragma unroll
    for (int j = 0; j < 4; ++j) {
      int col = wn * 64 + j * 16 + l;
#pragma unroll
      for (int r = 0; r < 4; ++r) {
        float v = acc[i][j][r];
        if (wm == 0) v = expf(fminf(v, 20.f));
        else         v = fminf(fmaxf(v, -1.0e4f), 1.0e4f);
        Ct[(row + r) * 136 + col] = __float2bfloat16(v);
      }
    }
  }
  __syncthreads();
  const int mi = wm, ni = wn;
#pragma unroll
  for (int hh = 0; hh < 2; ++hh) {
    f32x4 ca = {};
#pragma unroll
    for (int ks = 0; ks < 4; ++ks) {
      bf16x8 ea = *(const bf16x8*)&Ct[(hh * 32 + mi * 16 + l) * 136 + ks * 32 + quad * 8];
      bf16x8 vb = *(const bf16x8*)&Ct[(64 + hh * 32 + ni * 16 + l) * 136 + ks * 32 + quad * 8];
      ca = __builtin_amdgcn_mfma_f32_16x16x32_bf16(ea, vb, ca, 0, 0, 0);
    }
    int h = p * 2 + hh;
    float* cp = ctxb + (size_t)(b * HEADS + h) * DH * DH;
#pragma unroll
    for (int r = 0; r < 4; ++r)
      atomicAdd(&cp[(mi * 16 + quad * 4 + r) * DH + ni * 16 + l], ca[r]);
  }
  if (tid < 64) {
    int hh = tid >> 5, d = tid & 31;
    float s = 0.f;
#pragma unroll 16
    for (int c = 0; c < 128; ++c) s += __bfloat162float(Ct[tid * 136 + c]);
    atomicAdd(&sumexp[(b * HEADS + p * 2 + hh) * DH + d], s);
  }
}

// ---------------- kernel 3: W2 build (clamped) ----------------
__global__ __launch_bounds__(256) void w2_build_kernel(
    const void* __restrict__ wout, const int* __restrict__ mode,
    const float* __restrict__ ctxb, const float* __restrict__ sumexp,
    __hip_bfloat16* __restrict__ w2) {
  const bool f32 = mode[0] != 0;
  const int o = blockIdx.x;
  const int b = blockIdx.y;
  const int hd = threadIdx.x;
  const int h = hd >> 5, d = hd & 31;
  const float* cp = ctxb + ((size_t)(b * HEADS + h) * DH + d) * DH;
  float a = 0.f;
#pragma unroll
  for (int e = 0; e < DH; ++e) a += ldx(wout, (size_t)o * HID + h * DH + e, f32) * cp[e];
  float se = fmaxf(sumexp[(b * HEADS + h) * DH + d], 1e-30f);
  float v = a * QSCALE / se;
  v = fminf(fmaxf(v, -1.0e3f), 1.0e3f);
  w2[((size_t)b * CDIM + o) * HID + hd] = __float2bfloat16(v);
}

// ---------------- W3[b] = W2[b] (512x256) * Wq (256x512), bf16 sources ----------------
__global__ __launch_bounds__(256) void w3_gemm2_kernel(
    const __hip_bfloat16* __restrict__ w2, const __hip_bfloat16* __restrict__ wb,
    __hip_bfloat16* __restrict__ w3) {
  const int b = blockIdx.z;
  const int m0 = blockIdx.y * 128;
  const int n0 = blockIdx.x * 128;
  __shared__ __align__(16) __hip_bfloat16 As[128 * 40];
  __shared__ __align__(16) __hip_bfloat16 Bs[128 * 40];
  const int tid = threadIdx.x;
  const int lane = tid & 63;
  const int wv = tid >> 6;
  const int wm = wv >> 1, wn = wv & 1;
  const int quad = lane >> 4, l = lane & 15;
  f32x4 acc[4][4] = {};
  const int nn = tid & 127;
  const int cb = tid >> 7;
  const __hip_bfloat16* wa = w2 + (size_t)b * CDIM * HID;
  for (int k0 = 0; k0 < HID; k0 += 32) {
#pragma unroll
    for (int i = 0; i < 2; ++i) {
      int gid = tid + i * 256;
      int row = gid >> 2, c8 = (gid & 3) * 8;
      *(int4*)&As[row * 40 + c8] = *(const int4*)&wa[(size_t)(m0 + row) * HID + k0 + c8];
    }
#pragma unroll
    for (int r = 0; r < 16; ++r) {
      int hdl = r * 2 + cb;
      Bs[nn * 40 + hdl] = wb[(size_t)(k0 + hdl) * CDIM + n0 + nn];
    }
    __syncthreads();
    bf16x8 af[4], bfr[4];
#pragma unroll
    for (int i = 0; i < 4; ++i)
      af[i] = *(const bf16x8*)&As[(wm * 64 + i * 16 + l) * 40 + quad * 8];
#pragma unroll
    for (int j = 0; j < 4; ++j)
      bfr[j] = *(const bf16x8*)&Bs[(wn * 64 + j * 16 + l) * 40 + quad * 8];
#pragma unroll
    for (int i = 0; i < 4; ++i)
#pragma unroll
      for (int j = 0; j < 4; ++j)
        acc[i][j] = __builtin_amdgcn_mfma_f32_16x16x32_bf16(af[i], bfr[j], acc[i][j], 0, 0, 0);
    __syncthreads();
  }
#pragma unroll
  for (int i = 0; i < 4; ++i) {
    int orow = m0 + wm * 64 + i * 16 + quad * 4;
#pragma unroll
    for (int j = 0; j < 4; ++j) {
      int ncol = n0 + wn * 64 + j * 16 + l;
      __hip_bfloat16* op = w3 + ((size_t)b * CDIM + orow) * CDIM + ncol;
#pragma unroll
      for (int r = 0; r < 4; ++r) {
        float v = fminf(fmaxf(acc[i][j][r], -1.0e4f), 1.0e4f);
        op[(size_t)r * CDIM] = __float2bfloat16(v);
      }
    }
  }
}

// ---------------- legacy kernel 4: W3 GEMM ----------------
__global__ __launch_bounds__(256) void w3_gemm_kernel(
    const __hip_bfloat16* __restrict__ w2, const void* __restrict__ wqkv,
    const int* __restrict__ mode, __hip_bfloat16* __restrict__ w3) {
  const bool f32 = mode[0] != 0;
  const int b = blockIdx.z;
  const int m0 = blockIdx.y * 128;
  const int n0 = blockIdx.x * 128;
  __shared__ __align__(16) __hip_bfloat16 As[128 * 32];
  __shared__ __align__(16) __hip_bfloat16 Bs[128 * 40];
  const int tid = threadIdx.x;
  const int lane = tid & 63;
  const int wv = tid >> 6;
  const int wm = wv >> 1, wn = wv & 1;
  const int quad = lane >> 4, l = lane & 15;
  f32x4 acc[4][4] = {};
  const int nn = tid & 127;
  const int cb = tid >> 7;
  const __hip_bfloat16* wa = w2 + (size_t)b * CDIM * HID;
  for (int k0 = 0; k0 < HID; k0 += 32) {
#pragma unroll
    for (int r = 0; r < 2; ++r) {
      int idx = (r * 256 + tid) * 8;
      int row = idx >> 5, col = idx & 31;
      *(int4*)&As[idx] = *(const int4*)&wa[(size_t)(m0 + row) * HID + k0 + col];
    }
#pragma unroll
    for (int r = 0; r < 16; ++r) {
      int hdl = r * 2 + cb;
      Bs[nn * 40 + hdl] = __float2bfloat16(ldx(wqkv, (size_t)(k0 + hdl) * CDIM + n0 + nn, f32));
    }
    __syncthreads();
    bf16x8 af[4], bfr[4];
#pragma unroll
    for (int i = 0; i < 4; ++i)
      af[i] = *(const bf16x8*)&As[(wm * 64 + i * 16 + l) * 32 + quad * 8];
#pragma unroll
    for (int j = 0; j < 4; ++j)
      bfr[j] = *(const bf16x8*)&Bs[(wn * 64 + j * 16 + l) * 40 + quad * 8];
#pragma unroll
    for (int i = 0; i < 4; ++i)
#pragma unroll
      for (int j = 0; j < 4; ++j)
        acc[i][j] = __builtin_amdgcn_mfma_f32_16x16x32_bf16(af[i], bfr[j], acc[i][j], 0, 0, 0);
    __syncthreads();
  }
#pragma unroll
  for (int i = 0; i < 4; ++i) {
    int orow = m0 + wm * 64 + i * 16 + quad * 4;
#pragma unroll
    for (int j = 0; j < 4; ++j) {
      int ncol = n0 + wn * 64 + j * 16 + l;
      __hip_bfloat16* op = w3 + ((size_t)b * CDIM + orow) * CDIM + ncol;
#pragma unroll
      for (int r = 0; r < 4; ++r) {
        float v = fminf(fmaxf(acc[i][j][r], -1.0e4f), 1.0e4f);
        op[(size_t)r * CDIM] = __float2bfloat16(v);
      }
    }
  }
}

// ---------------- out = W3[b] * xnormT + b_out + x: 3-buffer counted-vmcnt pipeline ----------------
__global__ __launch_bounds__(256) void out_gemm5_kernel(
    const void* __restrict__ x, const __hip_bfloat16* __restrict__ w3,
    const __hip_bfloat16* __restrict__ xnt, const int* __restrict__ mode,
    const void* __restrict__ bout, void* __restrict__ out) {
  const bool f32 = mode[0] != 0;
  const int b = blockIdx.z;
  const int m0 = blockIdx.y * 128;
  const int n0 = blockIdx.x * 128;
  __shared__ __align__(16) char smem[49152];  // 3 x (As 8KB + Bs 8KB)
  const int tid = threadIdx.x;
  const int lane = tid & 63;
  const int wv = tid >> 6;
  const int wm = wv >> 1, wn = wv & 1;
  const int quad = lane >> 4, l = lane & 15;
  f32x4 acc[4][4] = {};
  const __hip_bfloat16* wa = w3 + (size_t)b * CDIM * CDIM;
  const __hip_bfloat16* xb = xnt + (size_t)b * NSEQ * CDIM;
  const int r16 = lane >> 2;
  const int cs8 = ((lane & 3) ^ (r16 & 3)) * 8;
  const int rowA = wv * 16 + r16;  // 0..63
  const int cq = (quad ^ (l & 3)) * 8;

#define OUT_STAGE(bufidx, k0) do {                                             \
    __hip_bfloat16* As_ = (__hip_bfloat16*)(smem + (bufidx) * 16384);          \
    __hip_bfloat16* Bs_ = As_ + 128 * 32;                                      \
    gld_lds16(&wa[(size_t)(m0 + rowA) * CDIM + (k0) + cs8],                    \
              &As_[(wv * 16) * 32]);                                           \
    gld_lds16(&wa[(size_t)(m0 + 64 + rowA) * CDIM + (k0) + cs8],               \
              &As_[(64 + wv * 16) * 32]);                                      \
    gld_lds16(&xb[(size_t)(n0 + rowA) * CDIM + (k0) + cs8],                    \
              &Bs_[(wv * 16) * 32]);                                           \
    gld_lds16(&xb[(size_t)(n0 + 64 + rowA) * CDIM + (k0) + cs8],               \
              &Bs_[(64 + wv * 16) * 32]);                                      \
  } while (0)

  OUT_STAGE(0, 0);
  OUT_STAGE(1, 32);
  for (int t = 0; t < 16; ++t) {
    if (t < 15) asm volatile("s_waitcnt vmcnt(4)" ::: "memory");
    else        asm volatile("s_waitcnt vmcnt(0)" ::: "memory");
    __builtin_amdgcn_s_barrier();
    __builtin_amdgcn_sched_barrier(0);
    if (t + 2 < 16) {
      int bi = (t + 2) % 3;
      OUT_STAGE(bi, (t + 2) * 32);
    }
    const __hip_bfloat16* As = (const __hip_bfloat16*)(smem + (t % 3) * 16384);
    const __hip_bfloat16* Bs = As + 128 * 32;
    bf16x8 af[4], bfr[4];
#pragma unroll
    for (int i = 0; i < 4; ++i)
      af[i] = *(const bf16x8*)&As[(wm * 64 + i * 16 + l) * 32 + cq];
#pragma unroll
    for (int j = 0; j < 4; ++j)
      bfr[j] = *(const bf16x8*)&Bs[(wn * 64 + j * 16 + l) * 32 + cq];
#pragma unroll
    for (int i = 0; i < 4; ++i)
#pragma unroll
      for (int j = 0; j < 4; ++j)
        acc[i][j] = __builtin_amdgcn_mfma_f32_16x16x32_bf16(af[i], bfr[j], acc[i][j], 0, 0, 0);
  }
#undef OUT_STAGE
#pragma unroll
  for (int i = 0; i < 4; ++i) {
    int orow = m0 + wm * 64 + i * 16 + quad * 4;
#pragma unroll
    for (int j = 0; j < 4; ++j) {
      int ncol = n0 + wn * 64 + j * 16 + l;
#pragma unroll
      for (int r = 0; r < 4; ++r) {
        size_t oi = ((size_t)b * CDIM + orow + r) * NSEQ + ncol;
        float v = acc[i][j][r] + ldx(bout, orow + r, f32) + ldx(x, oi, f32);
        stx(out, oi, f32, v);
      }
    }
  }
}

// ---------------- legacy kernel 5: out GEMM ----------------
__global__ __launch_bounds__(256) void out_gemm_kernel(
    const void* __restrict__ x, const void* __restrict__ g,
    const void* __restrict__ bln, const __hip_bfloat16* __restrict__ w3,
    const int* __restrict__ mode,
    const float* __restrict__ mean, const float* __restrict__ rstd,
    const void* __restrict__ bout, void* __restrict__ out) {
  const bool f32 = mode[0] != 0;
  const int b = blockIdx.z;
  const int m0 = blockIdx.y * 128;
  const int n0 = blockIdx.x * 128;
  __shared__ __align__(16) __hip_bfloat16 As[128 * 32];
  __shared__ __align__(16) __hip_bfloat16 Bs[128 * 40];
  const int tid = threadIdx.x;
  const int lane = tid & 63;
  const int wv = tid >> 6;
  const int wm = wv >> 1, wn = wv & 1;
  const int quad = lane >> 4, l = lane & 15;
  f32x4 acc[4][4] = {};
  const int nn = tid & 127;
  const int cb = tid >> 7;
  const float mn = mean[b * NSEQ + n0 + nn];
  const float rs = rstd[b * NSEQ + n0 + nn];
  const size_t xbase = (size_t)b * CDIM * NSEQ + n0 + nn;
  const __hip_bfloat16* wa = w3 + (size_t)b * CDIM * CDIM;
  for (int k0 = 0; k0 < CDIM; k0 += 32) {
#pragma unroll
    for (int r = 0; r < 2; ++r) {
      int idx = (r * 256 + tid) * 8;
      int row = idx >> 5, col = idx & 31;
      *(int4*)&As[idx] = *(const int4*)&wa[(size_t)(m0 + row) * CDIM + k0 + col];
    }
#pragma unroll
    for (int r = 0; r < 16; ++r) {
      int c = r * 2 + cb;
      float xv = ldx(x, xbase + (size_t)(k0 + c) * NSEQ, f32);
      float xn = (xv - mn) * rs;
      xn = xn * ldx(g, k0 + c, f32) + ldx(bln, k0 + c, f32);
      Bs[nn * 40 + c] = __float2bfloat16(xn);
    }
    __syncthreads();
    bf16x8 af[4], bfr[4];
#pragma unroll
    for (int i = 0; i < 4; ++i)
      af[i] = *(const bf16x8*)&As[(wm * 64 + i * 16 + l) * 32 + quad * 8];
#pragma unroll
    for (int j = 0; j < 4; ++j)
      bfr[j] = *(const bf16x8*)&Bs[(wn * 64 + j * 16 + l) * 40 + quad * 8];
#pragma unroll
    for (int i = 0; i < 4; ++i)
#pragma unroll
      for (int j = 0; j < 4; ++j)
        acc[i][j] = __builtin_amdgcn_mfma_f32_16x16x32_bf16(af[i], bfr[j], acc[i][j], 0, 0, 0);
    __syncthreads();
  }
#pragma unroll
  for (int i = 0; i < 4; ++i) {
    int orow = m0 + wm * 64 + i * 16 + quad * 4;
#pragma unroll
    for (int j = 0; j < 4; ++j) {
      int ncol = n0 + wn * 64 + j * 16 + l;
#pragma unroll
      for (int r = 0; r < 4; ++r) {
        size_t oi = ((size_t)b * CDIM + orow + r) * NSEQ + ncol;
        float v = acc[i][j][r] + ldx(bout, orow + r, f32) + ldx(x, oi, f32);
        stx(out, oi, f32, v);
      }
    }
  }
}

extern "C" void kernel_launch(void* const* d_in, const int* in_sizes, int n_in,
                              void* d_out, int out_size, void* d_ws, size_t ws_size,
                              hipStream_t stream) {
  (void)in_sizes; (void)n_in; (void)out_size;
  const void* x    = d_in[0];
  const void* g    = d_in[1];
  const void* bln  = d_in[2];
  const void* wqkv = d_in[3];
  const void* wout = d_in[4];
  const void* bout = d_in[5];

  float* mean   = (float*)d_ws;                    // 8*8192
  float* rstd   = mean + BATCH * NSEQ;             // 8*8192
  float* ctxb   = rstd + BATCH * NSEQ;             // 65536
  float* sumexp = ctxb + BATCH * HEADS * DH * DH;  // 2048
  int*   mode   = (int*)(sumexp + BATCH * HEADS * DH);
  __hip_bfloat16* w2  = (__hip_bfloat16*)(mode + 64);            // 8*512*256
  __hip_bfloat16* w3  = w2 + (size_t)BATCH * CDIM * HID;         // 8*512*512
  __hip_bfloat16* wb  = w3 + (size_t)BATCH * CDIM * CDIM;        // 768*512
  __hip_bfloat16* xnt = wb + (size_t)O3 * CDIM;                  // 8*8192*512
  const size_t need = (size_t)((const char*)(xnt + (size_t)BATCH * NSEQ * CDIM) - (const char*)d_ws);

  hipMemsetAsync(ctxb, 0, (BATCH * HEADS * DH * DH + BATCH * HEADS * DH) * sizeof(float), stream);
  detect_kernel<<<1, 256, 0, stream>>>(x, mode);

  if (ws_size >= need) {
    ln_stats4_kernel<<<dim3(NSEQ / 128, BATCH), 256, 0, stream>>>(x, mode, mean, rstd);
    wconv_kernel<<<dim3((O3 * CDIM) / 2048), 256, 0, stream>>>(wqkv, mode, wb);
    xnormt_kernel<<<dim3(NSEQ / 128, CDIM / 128, BATCH), 256, 0, stream>>>(
        x, g, bln, mode, mean, rstd, xnt);
    kv_gemm5_kernel<<<dim3(NSEQ / 128, HEADS / 2, BATCH), 256, 0, stream>>>(
        wb, xnt, ctxb, sumexp);
    w2_build_kernel<<<dim3(CDIM, BATCH), 256, 0, stream>>>(wout, mode, ctxb, sumexp, w2);
    w3_gemm2_kernel<<<dim3(CDIM / 128, CDIM / 128, BATCH), 256, 0, stream>>>(w2, wb, w3);
    out_gemm5_kernel<<<dim3(NSEQ / 128, CDIM / 128, BATCH), 256, 0, stream>>>(
        x, w3, xnt, mode, bout, d_out);
  } else {
    ln_stats_kernel<<<dim3(NSEQ / 64, BATCH), 256, 0, stream>>>(x, mode, mean, rstd);
    kvctx_kernel<<<dim3(NSEQ / 128, HEADS / 2, BATCH), 256, 0, stream>>>(
        x, g, bln, wqkv, mode, mean, rstd, ctxb, sumexp);
    w2_build_kernel<<<dim3(CDIM, BATCH), 256, 0, stream>>>(wout, mode, ctxb, sumexp, w2);
    w3_gemm_kernel<<<dim3(CDIM / 128, CDIM / 128, BATCH), 256, 0, stream>>>(w2, wqkv, mode, w3);
    out_gemm_kernel<<<dim3(NSEQ / 128, CDIM / 128, BATCH), 256, 0, stream>>>(
        x, g, bln, w3, mode, mean, rstd, bout, d_out);
  }
}

// Round 6
// 547.443 us; speedup vs baseline: 2.3087x; 1.0525x over previous
//
#include <hip/hip_runtime.h>
#include <hip/hip_bf16.h>
#include <math.h>

#define HEADS 8
#define DH 32
#define BATCH 8
#define CDIM 512
#define NSEQ 8192
#define HID 256
#define O3 768
#define LNEPS 1e-5f
#define QSCALE 0.1767766952966369f  // 32^-0.5

typedef __bf16 bf16x8 __attribute__((ext_vector_type(8)));
typedef float f32x4 __attribute__((ext_vector_type(4)));
typedef unsigned short u16;
typedef u16 u16x4 __attribute__((ext_vector_type(4)));
typedef u16 u16x8 __attribute__((ext_vector_type(8)));

// async global->LDS 16B copy: LDS dest is wave-uniform base + lane*16 (m97 pattern)
__device__ __forceinline__ void gld_lds16(const void* g, void* l) {
  __builtin_amdgcn_global_load_lds(
      (const __attribute__((address_space(1))) unsigned int*)g,
      (__attribute__((address_space(3))) unsigned int*)l, 16, 0, 0);
}

// dual-dtype element load: mode==1 -> fp32 buffer, mode==0 -> bf16 buffer
__device__ __forceinline__ float ldx(const void* p, size_t i, bool f32) {
  if (f32) {
    float v = ((const float*)p)[i];
    return __builtin_isfinite(v) ? v : 0.f;
  }
  return __bfloat162float(((const __hip_bfloat16*)p)[i]);
}

__device__ __forceinline__ u16 b16(float v) {
  union { __hip_bfloat16 h; u16 u; } cv;
  cv.h = __float2bfloat16(v);
  return cv.u;
}

__device__ __forceinline__ float fb16(u16 u) {
  return __uint_as_float((unsigned)u << 16);
}

// stage 8 contiguous elements into LDS as bf16 (legacy path)
__device__ __forceinline__ void stage8(__hip_bfloat16* dst, const void* src, size_t idx, bool f32) {
  if (f32) {
    const float* s = (const float*)src + idx;
#pragma unroll
    for (int t = 0; t < 8; ++t) {
      float v = s[t];
      if (!__builtin_isfinite(v)) v = 0.f;
      dst[t] = __float2bfloat16(v);
    }
  } else {
    *(int4*)dst = *(const int4*)((const __hip_bfloat16*)src + idx);
  }
}

// dual-dtype store with finite scrub
__device__ __forceinline__ void stx(void* p, size_t i, bool f32, float v) {
  if (!__builtin_isfinite(v)) v = 0.f;
  if (f32) ((float*)p)[i] = v;
  else ((__hip_bfloat16*)p)[i] = __float2bfloat16(v);
}

// ---------------- kernel 0: dtype detector ----------------
__global__ __launch_bounds__(256) void detect_kernel(const void* __restrict__ x, int* __restrict__ mode) {
  __shared__ int cnt;
  if (threadIdx.x == 0) cnt = 0;
  __syncthreads();
  const __hip_bfloat16* p = (const __hip_bfloat16*)x;
  int c = 0;
  for (int i = threadIdx.x; i < 4096; i += 256) {
    float v = __bfloat162float(p[i]);
    if (!(v > -1.0e3f && v < 1.0e3f)) c++;
  }
  atomicAdd(&cnt, c);
  __syncthreads();
  if (threadIdx.x == 0) mode[0] = (cnt > 64) ? 1 : 0;
}

// ---------------- LN stats, float4-vectorized ----------------
__global__ __launch_bounds__(256) void ln_stats4_kernel(
    const void* __restrict__ x, const int* __restrict__ mode,
    float* __restrict__ mean, float* __restrict__ rstd) {
  const bool f32 = mode[0] != 0;
  const int b = blockIdx.y;
  const int n0 = blockIdx.x * 128;
  const int t = threadIdx.x;
  const int m = t & 31, cp = t >> 5;
  const int n4 = m * 4;
  const size_t base = (size_t)b * CDIM * NSEQ + n0 + n4;
  f32x4 s = {0.f, 0.f, 0.f, 0.f}, q = {0.f, 0.f, 0.f, 0.f};
  for (int c = cp * 64; c < cp * 64 + 64; ++c) {
    f32x4 v;
    if (f32) {
      v = *(const f32x4*)((const float*)x + base + (size_t)c * NSEQ);
#pragma unroll
      for (int j = 0; j < 4; ++j) if (!__builtin_isfinite(v[j])) v[j] = 0.f;
    } else {
      u16x4 h = *(const u16x4*)((const __hip_bfloat16*)x + base + (size_t)c * NSEQ);
#pragma unroll
      for (int j = 0; j < 4; ++j) v[j] = fb16(h[j]);
    }
    s += v;
    q += v * v;
  }
  __shared__ f32x4 sbS[8][32], sbQ[8][32];
  sbS[cp][m] = s; sbQ[cp][m] = q;
  __syncthreads();
  if (t < 32) {
    f32x4 S = sbS[0][t], Q = sbQ[0][t];
#pragma unroll
    for (int k = 1; k < 8; ++k) { S += sbS[k][t]; Q += sbQ[k][t]; }
    f32x4 M = S * (1.f / CDIM);
    f32x4 V = Q * (1.f / CDIM) - M * M;
#pragma unroll
    for (int j = 0; j < 4; ++j) {
      mean[b * NSEQ + n0 + t * 4 + j] = M[j];
      rstd[b * NSEQ + n0 + t * 4 + j] = rsqrtf(fmaxf(V[j], 0.f) + LNEPS);
    }
  }
}

// ---------------- wqkv -> bf16 once ----------------
__global__ __launch_bounds__(256) void wconv_kernel(
    const void* __restrict__ wqkv, const int* __restrict__ mode,
    __hip_bfloat16* __restrict__ wb) {
  const bool f32 = mode[0] != 0;
  const size_t i = ((size_t)blockIdx.x * 256 + threadIdx.x) * 8;
  if (f32) {
    f32x4 a = *(const f32x4*)((const float*)wqkv + i);
    f32x4 c = *(const f32x4*)((const float*)wqkv + i + 4);
    u16x8 o;
#pragma unroll
    for (int j = 0; j < 4; ++j) {
      float va = __builtin_isfinite(a[j]) ? a[j] : 0.f;
      float vc = __builtin_isfinite(c[j]) ? c[j] : 0.f;
      o[j] = b16(va);
      o[4 + j] = b16(vc);
    }
    *(u16x8*)&wb[i] = o;
  } else {
    *(int4*)&wb[i] = *(const int4*)((const __hip_bfloat16*)wqkv + i);
  }
}

// ---------------- xnormT[b][n][c] bf16 via LDS transpose ----------------
__global__ __launch_bounds__(256) void xnormt_kernel(
    const void* __restrict__ x, const void* __restrict__ g, const void* __restrict__ bln,
    const int* __restrict__ mode, const float* __restrict__ mean, const float* __restrict__ rstd,
    __hip_bfloat16* __restrict__ xnt) {
  const bool f32 = mode[0] != 0;
  const int b = blockIdx.z;
  const int c0 = blockIdx.y * 128;
  const int n0 = blockIdx.x * 128;
  __shared__ u16 tile[128 * 132];
  const int t = threadIdx.x;
  const int m = t & 31, rb = t >> 5;
  const int n4 = m * 4;
  const f32x4 mn = *(const f32x4*)&mean[b * NSEQ + n0 + n4];
  const f32x4 rs = *(const f32x4*)&rstd[b * NSEQ + n0 + n4];
#pragma unroll
  for (int it = 0; it < 16; ++it) {
    const int r = it * 8 + rb;
    const float gv = ldx(g, c0 + r, f32);
    const float bv = ldx(bln, c0 + r, f32);
    const size_t src = ((size_t)b * CDIM + c0 + r) * NSEQ + n0 + n4;
    f32x4 v;
    if (f32) {
      v = *(const f32x4*)((const float*)x + src);
#pragma unroll
      for (int j = 0; j < 4; ++j) if (!__builtin_isfinite(v[j])) v[j] = 0.f;
    } else {
      u16x4 h = *(const u16x4*)((const __hip_bfloat16*)x + src);
#pragma unroll
      for (int j = 0; j < 4; ++j) v[j] = fb16(h[j]);
    }
    u16x4 o;
#pragma unroll
    for (int j = 0; j < 4; ++j) o[j] = b16((v[j] - mn[j]) * rs[j] * gv + bv);
    *(u16x4*)&tile[r * 132 + n4] = o;
  }
  __syncthreads();
  const int n = t >> 1, ch = t & 1;
  __hip_bfloat16* dst = xnt + ((size_t)b * NSEQ + n0 + n) * CDIM + c0 + ch * 64;
#pragma unroll
  for (int i8 = 0; i8 < 8; ++i8) {
    u16x8 o;
#pragma unroll
    for (int k = 0; k < 8; ++k) o[k] = tile[(ch * 64 + i8 * 8 + k) * 132 + n];
    *(u16x8*)(dst + i8 * 8) = o;
  }
}

// ---------------- legacy kernel 1: LayerNorm stats ----------------
__global__ __launch_bounds__(256) void ln_stats_kernel(
    const void* __restrict__ x, const int* __restrict__ mode,
    float* __restrict__ mean, float* __restrict__ rstd) {
  const bool f32 = mode[0] != 0;
  int b = blockIdx.y;
  int nl = threadIdx.x & 63;
  int cp = threadIdx.x >> 6;
  int n = blockIdx.x * 64 + nl;
  size_t base = (size_t)b * CDIM * NSEQ + n;
  float s = 0.f, ss = 0.f;
  for (int c = cp * 128; c < cp * 128 + 128; ++c) {
    float v = ldx(x, base + (size_t)c * NSEQ, f32);
    s += v; ss += v * v;
  }
  __shared__ float sb[4][64], sb2[4][64];
  sb[cp][nl] = s; sb2[cp][nl] = ss;
  __syncthreads();
  if (cp == 0) {
    s = sb[0][nl] + sb[1][nl] + sb[2][nl] + sb[3][nl];
    ss = sb2[0][nl] + sb2[1][nl] + sb2[2][nl] + sb2[3][nl];
    float m = s * (1.f / CDIM);
    float var = ss * (1.f / CDIM) - m * m;
    mean[b * NSEQ + n] = m;
    rstd[b * NSEQ + n] = rsqrtf(fmaxf(var, 0.f) + LNEPS);
  }
}

// ---------------- K/V GEMM + exp + context: 8-wave BN=256, 3-stage counted-vmcnt ----------------
__global__ __launch_bounds__(512) void kv_gemm6_kernel(
    const __hip_bfloat16* __restrict__ wb, const __hip_bfloat16* __restrict__ xnt,
    float* __restrict__ ctxb, float* __restrict__ sumexp) {
  const int b = blockIdx.z;
  const int p = blockIdx.y;
  const int n0 = blockIdx.x * 256;
  // union: 3 x 24KB (As 8KB + Bs 16KB) / Ct 128x264 bf16 (67.5KB)
  __shared__ __align__(16) char smem[73728];
  __hip_bfloat16* Ct = (__hip_bfloat16*)smem;
  const int tid = threadIdx.x;
  const int lane = tid & 63;
  const int wv = tid >> 6;             // 0..7
  const int wm = wv >> 2, wn = wv & 3; // 2 x 4 wave grid
  const int quad = lane >> 4, l = lane & 15;
  f32x4 acc[4][4] = {};
  const __hip_bfloat16* xb = xnt + (size_t)b * NSEQ * CDIM;
  const int r16 = lane >> 2;
  const int cs8 = ((lane & 3) ^ (r16 & 3)) * 8;  // swizzled source chunk
  const int cq = (quad ^ (l & 3)) * 8;           // swizzled read chunk
  const int rowA = wv * 16 + r16;                // 0..127
  const int srowA = (rowA < 64) ? (256 + p * 64 + rowA) : (512 + p * 64 + (rowA - 64));
  const int rowB = wv * 32 + r16;

#define KV_STAGE(bufidx, k0) do {                                              \
    __hip_bfloat16* As_ = (__hip_bfloat16*)(smem + (bufidx) * 24576);          \
    __hip_bfloat16* Bs_ = As_ + 128 * 32;                                      \
    gld_lds16(&wb[(size_t)srowA * CDIM + (k0) + cs8], &As_[(wv * 16) * 32]);   \
    gld_lds16(&xb[(size_t)(n0 + rowB) * CDIM + (k0) + cs8],                    \
              &Bs_[(wv * 32) * 32]);                                           \
    gld_lds16(&xb[(size_t)(n0 + rowB + 16) * CDIM + (k0) + cs8],               \
              &Bs_[(wv * 32 + 16) * 32]);                                      \
  } while (0)

  KV_STAGE(0, 0);
  KV_STAGE(1, 32);
  for (int t = 0; t < 16; ++t) {
    if (t < 15) asm volatile("s_waitcnt vmcnt(3)" ::: "memory");
    else        asm volatile("s_waitcnt vmcnt(0)" ::: "memory");
    __builtin_amdgcn_s_barrier();
    __builtin_amdgcn_sched_barrier(0);
    if (t + 2 < 16) KV_STAGE((t + 2) % 3, (t + 2) * 32);
    const __hip_bfloat16* As = (const __hip_bfloat16*)(smem + (t % 3) * 24576);
    const __hip_bfloat16* Bs = As + 128 * 32;
    bf16x8 af[4], bfr[4];
#pragma unroll
    for (int i = 0; i < 4; ++i)
      af[i] = *(const bf16x8*)&As[(wm * 64 + i * 16 + l) * 32 + cq];
#pragma unroll
    for (int j = 0; j < 4; ++j)
      bfr[j] = *(const bf16x8*)&Bs[(wn * 64 + j * 16 + l) * 32 + cq];
#pragma unroll
    for (int i = 0; i < 4; ++i)
#pragma unroll
      for (int j = 0; j < 4; ++j)
        acc[i][j] = __builtin_amdgcn_mfma_f32_16x16x32_bf16(af[i], bfr[j], acc[i][j], 0, 0, 0);
  }
#undef KV_STAGE
  __syncthreads();  // all ds_reads done; safe to reuse smem as Ct
  // epilogue: exp on K half (rows 0..63 = wm 0), clamp V half; write C tile to LDS
#pragma unroll
  for (int i = 0; i < 4; ++i) {
    int row = wm * 64 + i * 16 + quad * 4;
#pragma unroll
    for (int j = 0; j < 4; ++j) {
      int col = wn * 64 + j * 16 + l;
#pragma unroll
      for (int r = 0; r < 4; ++r) {
        float v = acc[i][j][r];
        if (wm == 0) v = expf(fminf(v, 20.f));
        else         v = fminf(fmaxf(v, -1.0e4f), 1.0e4f);
        Ct[(row + r) * 264 + col] = __float2bfloat16(v);
      }
    }
  }
  __syncthreads();
  // ctx: waves split k-chunks (kh) and ni; partial sums via atomics
  const int mi = wm, ni = wn & 1, kh = wn >> 1;
#pragma unroll
  for (int hh = 0; hh < 2; ++hh) {
    f32x4 ca = {};
#pragma unroll
    for (int ks = 0; ks < 4; ++ks) {
      int kk = kh * 4 + ks;
      bf16x8 ea = *(const bf16x8*)&Ct[(hh * 32 + mi * 16 + l) * 264 + kk * 32 + quad * 8];
      bf16x8 vb = *(const bf16x8*)&Ct[(64 + hh * 32 + ni * 16 + l) * 264 + kk * 32 + quad * 8];
      ca = __builtin_amdgcn_mfma_f32_16x16x32_bf16(ea, vb, ca, 0, 0, 0);
    }
    int h = p * 2 + hh;
    float* cp = ctxb + (size_t)(b * HEADS + h) * DH * DH;
#pragma unroll
    for (int r = 0; r < 4; ++r)
      atomicAdd(&cp[(mi * 16 + quad * 4 + r) * DH + ni * 16 + l], ca[r]);
  }
  if (tid < 64) {
    int hh = tid >> 5, d = tid & 31;
    float s = 0.f;
#pragma unroll
    for (int c8 = 0; c8 < 32; ++c8) {
      u16x8 h8 = *(const u16x8*)&Ct[tid * 264 + c8 * 8];
#pragma unroll
      for (int k = 0; k < 8; ++k) s += fb16(h8[k]);
    }
    atomicAdd(&sumexp[(b * HEADS + p * 2 + hh) * DH + d], s);
  }
}

// ---------------- legacy kernel 2: fused K/V GEMM + exp + context ----------------
__global__ __launch_bounds__(256) void kvctx_kernel(
    const void* __restrict__ x, const void* __restrict__ g,
    const void* __restrict__ bln, const void* __restrict__ wqkv,
    const int* __restrict__ mode,
    const float* __restrict__ mean, const float* __restrict__ rstd,
    float* __restrict__ ctxb, float* __restrict__ sumexp) {
  const bool f32 = mode[0] != 0;
  const int b = blockIdx.z;
  const int p = blockIdx.y;
  const int n0 = blockIdx.x * 128;
  __shared__ __align__(16) __hip_bfloat16 As[128 * 32];
  __shared__ __align__(16) __hip_bfloat16 Bs[128 * 40];
  __shared__ __align__(16) __hip_bfloat16 Ct[128 * 136];
  const int tid = threadIdx.x;
  const int lane = tid & 63;
  const int wv = tid >> 6;
  const int wm = wv >> 1, wn = wv & 1;
  const int quad = lane >> 4, l = lane & 15;
  f32x4 acc[4][4] = {};
  const int nn = tid & 127;
  const int cb = tid >> 7;
  const float mn = mean[b * NSEQ + n0 + nn];
  const float rs = rstd[b * NSEQ + n0 + nn];
  const size_t xbase = (size_t)b * CDIM * NSEQ + n0 + nn;
  for (int k0 = 0; k0 < CDIM; k0 += 32) {
#pragma unroll
    for (int r = 0; r < 2; ++r) {
      int idx = (r * 256 + tid) * 8;
      int row = idx >> 5, col = idx & 31;
      int srow = (row < 64) ? (256 + p * 64 + row) : (512 + p * 64 + row - 64);
      stage8(&As[idx], wqkv, (size_t)srow * CDIM + k0 + col, f32);
    }
#pragma unroll
    for (int r = 0; r < 16; ++r) {
      int c = r * 2 + cb;
      float xv = ldx(x, xbase + (size_t)(k0 + c) * NSEQ, f32);
      float xn = (xv - mn) * rs;
      xn = xn * ldx(g, k0 + c, f32) + ldx(bln, k0 + c, f32);
      Bs[nn * 40 + c] = __float2bfloat16(xn);
    }
    __syncthreads();
    bf16x8 af[4], bfr[4];
#pragma unroll
    for (int i = 0; i < 4; ++i)
      af[i] = *(const bf16x8*)&As[(wm * 64 + i * 16 + l) * 32 + quad * 8];
#pragma unroll
    for (int j = 0; j < 4; ++j)
      bfr[j] = *(const bf16x8*)&Bs[(wn * 64 + j * 16 + l) * 40 + quad * 8];
#pragma unroll
    for (int i = 0; i < 4; ++i)
#pragma unroll
      for (int j = 0; j < 4; ++j)
        acc[i][j] = __builtin_amdgcn_mfma_f32_16x16x32_bf16(af[i], bfr[j], acc[i][j], 0, 0, 0);
    __syncthreads();
  }
#pragma unroll
  for (int i = 0; i < 4; ++i) {
    int row = wm * 64 + i * 16 + quad * 4;
#pragma unroll
    for (int j = 0; j < 4; ++j) {
      int col = wn * 64 + j * 16 + l;
#pragma unroll
      for (int r = 0; r < 4; ++r) {
        float v = acc[i][j][r];
        if (wm == 0) v = expf(fminf(v, 20.f));
        else         v = fminf(fmaxf(v, -1.0e4f), 1.0e4f);
        Ct[(row + r) * 136 + col] = __float2bfloat16(v);
      }
    }
  }
  __syncthreads();
  const int mi = wm, ni = wn;
#pragma unroll
  for (int hh = 0; hh < 2; ++hh) {
    f32x4 ca = {};
#pragma unroll
    for (int ks = 0; ks < 4; ++ks) {
      bf16x8 ea = *(const bf16x8*)&Ct[(hh * 32 + mi * 16 + l) * 136 + ks * 32 + quad * 8];
      bf16x8 vb = *(const bf16x8*)&Ct[(64 + hh * 32 + ni * 16 + l) * 136 + ks * 32 + quad * 8];
      ca = __builtin_amdgcn_mfma_f32_16x16x32_bf16(ea, vb, ca, 0, 0, 0);
    }
    int h = p * 2 + hh;
    float* cp = ctxb + (size_t)(b * HEADS + h) * DH * DH;
#pragma unroll
    for (int r = 0; r < 4; ++r)
      atomicAdd(&cp[(mi * 16 + quad * 4 + r) * DH + ni * 16 + l], ca[r]);
  }
  if (tid < 64) {
    int hh = tid >> 5, d = tid & 31;
    float s = 0.f;
#pragma unroll 16
    for (int c = 0; c < 128; ++c) s += __bfloat162float(Ct[tid * 136 + c]);
    atomicAdd(&sumexp[(b * HEADS + p * 2 + hh) * DH + d], s);
  }
}

// ---------------- kernel 3: W2 build (clamped) ----------------
__global__ __launch_bounds__(256) void w2_build_kernel(
    const void* __restrict__ wout, const int* __restrict__ mode,
    const float* __restrict__ ctxb, const float* __restrict__ sumexp,
    __hip_bfloat16* __restrict__ w2) {
  const bool f32 = mode[0] != 0;
  const int o = blockIdx.x;
  const int b = blockIdx.y;
  const int hd = threadIdx.x;
  const int h = hd >> 5, d = hd & 31;
  const float* cp = ctxb + ((size_t)(b * HEADS + h) * DH + d) * DH;
  float a = 0.f;
#pragma unroll
  for (int e = 0; e < DH; ++e) a += ldx(wout, (size_t)o * HID + h * DH + e, f32) * cp[e];
  float se = fmaxf(sumexp[(b * HEADS + h) * DH + d], 1e-30f);
  float v = a * QSCALE / se;
  v = fminf(fmaxf(v, -1.0e3f), 1.0e3f);
  w2[((size_t)b * CDIM + o) * HID + hd] = __float2bfloat16(v);
}

// ---------------- W3[b] = W2[b] (512x256) * Wq (256x512), bf16 sources ----------------
__global__ __launch_bounds__(256) void w3_gemm2_kernel(
    const __hip_bfloat16* __restrict__ w2, const __hip_bfloat16* __restrict__ wb,
    __hip_bfloat16* __restrict__ w3) {
  const int b = blockIdx.z;
  const int m0 = blockIdx.y * 128;
  const int n0 = blockIdx.x * 128;
  __shared__ __align__(16) __hip_bfloat16 As[128 * 40];
  __shared__ __align__(16) __hip_bfloat16 Bs[128 * 40];
  const int tid = threadIdx.x;
  const int lane = tid & 63;
  const int wv = tid >> 6;
  const int wm = wv >> 1, wn = wv & 1;
  const int quad = lane >> 4, l = lane & 15;
  f32x4 acc[4][4] = {};
  const int nn = tid & 127;
  const int cb = tid >> 7;
  const __hip_bfloat16* wa = w2 + (size_t)b * CDIM * HID;
  for (int k0 = 0; k0 < HID; k0 += 32) {
#pragma unroll
    for (int i = 0; i < 2; ++i) {
      int gid = tid + i * 256;
      int row = gid >> 2, c8 = (gid & 3) * 8;
      *(int4*)&As[row * 40 + c8] = *(const int4*)&wa[(size_t)(m0 + row) * HID + k0 + c8];
    }
#pragma unroll
    for (int r = 0; r < 16; ++r) {
      int hdl = r * 2 + cb;
      Bs[nn * 40 + hdl] = wb[(size_t)(k0 + hdl) * CDIM + n0 + nn];
    }
    __syncthreads();
    bf16x8 af[4], bfr[4];
#pragma unroll
    for (int i = 0; i < 4; ++i)
      af[i] = *(const bf16x8*)&As[(wm * 64 + i * 16 + l) * 40 + quad * 8];
#pragma unroll
    for (int j = 0; j < 4; ++j)
      bfr[j] = *(const bf16x8*)&Bs[(wn * 64 + j * 16 + l) * 40 + quad * 8];
#pragma unroll
    for (int i = 0; i < 4; ++i)
#pragma unroll
      for (int j = 0; j < 4; ++j)
        acc[i][j] = __builtin_amdgcn_mfma_f32_16x16x32_bf16(af[i], bfr[j], acc[i][j], 0, 0, 0);
    __syncthreads();
  }
#pragma unroll
  for (int i = 0; i < 4; ++i) {
    int orow = m0 + wm * 64 + i * 16 + quad * 4;
#pragma unroll
    for (int j = 0; j < 4; ++j) {
      int ncol = n0 + wn * 64 + j * 16 + l;
      __hip_bfloat16* op = w3 + ((size_t)b * CDIM + orow) * CDIM + ncol;
#pragma unroll
      for (int r = 0; r < 4; ++r) {
        float v = fminf(fmaxf(acc[i][j][r], -1.0e4f), 1.0e4f);
        op[(size_t)r * CDIM] = __float2bfloat16(v);
      }
    }
  }
}

// ---------------- legacy kernel 4: W3 GEMM ----------------
__global__ __launch_bounds__(256) void w3_gemm_kernel(
    const __hip_bfloat16* __restrict__ w2, const void* __restrict__ wqkv,
    const int* __restrict__ mode, __hip_bfloat16* __restrict__ w3) {
  const bool f32 = mode[0] != 0;
  const int b = blockIdx.z;
  const int m0 = blockIdx.y * 128;
  const int n0 = blockIdx.x * 128;
  __shared__ __align__(16) __hip_bfloat16 As[128 * 32];
  __shared__ __align__(16) __hip_bfloat16 Bs[128 * 40];
  const int tid = threadIdx.x;
  const int lane = tid & 63;
  const int wv = tid >> 6;
  const int wm = wv >> 1, wn = wv & 1;
  const int quad = lane >> 4, l = lane & 15;
  f32x4 acc[4][4] = {};
  const int nn = tid & 127;
  const int cb = tid >> 7;
  const __hip_bfloat16* wa = w2 + (size_t)b * CDIM * HID;
  for (int k0 = 0; k0 < HID; k0 += 32) {
#pragma unroll
    for (int r = 0; r < 2; ++r) {
      int idx = (r * 256 + tid) * 8;
      int row = idx >> 5, col = idx & 31;
      *(int4*)&As[idx] = *(const int4*)&wa[(size_t)(m0 + row) * HID + k0 + col];
    }
#pragma unroll
    for (int r = 0; r < 16; ++r) {
      int hdl = r * 2 + cb;
      Bs[nn * 40 + hdl] = __float2bfloat16(ldx(wqkv, (size_t)(k0 + hdl) * CDIM + n0 + nn, f32));
    }
    __syncthreads();
    bf16x8 af[4], bfr[4];
#pragma unroll
    for (int i = 0; i < 4; ++i)
      af[i] = *(const bf16x8*)&As[(wm * 64 + i * 16 + l) * 32 + quad * 8];
#pragma unroll
    for (int j = 0; j < 4; ++j)
      bfr[j] = *(const bf16x8*)&Bs[(wn * 64 + j * 16 + l) * 40 + quad * 8];
#pragma unroll
    for (int i = 0; i < 4; ++i)
#pragma unroll
      for (int j = 0; j < 4; ++j)
        acc[i][j] = __builtin_amdgcn_mfma_f32_16x16x32_bf16(af[i], bfr[j], acc[i][j], 0, 0, 0);
    __syncthreads();
  }
#pragma unroll
  for (int i = 0; i < 4; ++i) {
    int orow = m0 + wm * 64 + i * 16 + quad * 4;
#pragma unroll
    for (int j = 0; j < 4; ++j) {
      int ncol = n0 + wn * 64 + j * 16 + l;
      __hip_bfloat16* op = w3 + ((size_t)b * CDIM + orow) * CDIM + ncol;
#pragma unroll
      for (int r = 0; r < 4; ++r) {
        float v = fminf(fmaxf(acc[i][j][r], -1.0e4f), 1.0e4f);
        op[(size_t)r * CDIM] = __float2bfloat16(v);
      }
    }
  }
}

// ---------------- out = W3[b] * xnormT + b_out + x: 8-wave BN=256, 3-stage counted-vmcnt ----------------
__global__ __launch_bounds__(512) void out_gemm6_kernel(
    const void* __restrict__ x, const __hip_bfloat16* __restrict__ w3,
    const __hip_bfloat16* __restrict__ xnt, const int* __restrict__ mode,
    const void* __restrict__ bout, void* __restrict__ out) {
  const bool f32 = mode[0] != 0;
  const int b = blockIdx.z;
  const int m0 = blockIdx.y * 128;
  const int n0 = blockIdx.x * 256;
  __shared__ __align__(16) char smem[73728];  // 3 x (As 8KB + Bs 16KB)
  const int tid = threadIdx.x;
  const int lane = tid & 63;
  const int wv = tid >> 6;             // 0..7
  const int wm = wv >> 2, wn = wv & 3; // 2 x 4 wave grid
  const int quad = lane >> 4, l = lane & 15;
  f32x4 acc[4][4] = {};
  const __hip_bfloat16* wa = w3 + (size_t)b * CDIM * CDIM;
  const __hip_bfloat16* xb = xnt + (size_t)b * NSEQ * CDIM;
  const int r16 = lane >> 2;
  const int cs8 = ((lane & 3) ^ (r16 & 3)) * 8;
  const int cq = (quad ^ (l & 3)) * 8;
  const int rowA = wv * 16 + r16;   // 0..127 (w3 rows)
  const int rowB = wv * 32 + r16;   // B rows base

#define OUT_STAGE(bufidx, k0) do {                                             \
    __hip_bfloat16* As_ = (__hip_bfloat16*)(smem + (bufidx) * 24576);          \
    __hip_bfloat16* Bs_ = As_ + 128 * 32;                                      \
    gld_lds16(&wa[(size_t)(m0 + rowA) * CDIM + (k0) + cs8],                    \
              &As_[(wv * 16) * 32]);                                           \
    gld_lds16(&xb[(size_t)(n0 + rowB) * CDIM + (k0) + cs8],                    \
              &Bs_[(wv * 32) * 32]);                                           \
    gld_lds16(&xb[(size_t)(n0 + rowB + 16) * CDIM + (k0) + cs8],               \
              &Bs_[(wv * 32 + 16) * 32]);                                      \
  } while (0)

  OUT_STAGE(0, 0);
  OUT_STAGE(1, 32);
  for (int t = 0; t < 16; ++t) {
    if (t < 15) asm volatile("s_waitcnt vmcnt(3)" ::: "memory");
    else        asm volatile("s_waitcnt vmcnt(0)" ::: "memory");
    __builtin_amdgcn_s_barrier();
    __builtin_amdgcn_sched_barrier(0);
    if (t + 2 < 16) OUT_STAGE((t + 2) % 3, (t + 2) * 32);
    const __hip_bfloat16* As = (const __hip_bfloat16*)(smem + (t % 3) * 24576);
    const __hip_bfloat16* Bs = As + 128 * 32;
    bf16x8 af[4], bfr[4];
#pragma unroll
    for (int i = 0; i < 4; ++i)
      af[i] = *(const bf16x8*)&As[(wm * 64 + i * 16 + l) * 32 + cq];
#pragma unroll
    for (int j = 0; j < 4; ++j)
      bfr[j] = *(const bf16x8*)&Bs[(wn * 64 + j * 16 + l) * 32 + cq];
#pragma unroll
    for (int i = 0; i < 4; ++i)
#pragma unroll
      for (int j = 0; j < 4; ++j)
        acc[i][j] = __builtin_amdgcn_mfma_f32_16x16x32_bf16(af[i], bfr[j], acc[i][j], 0, 0, 0);
  }
#undef OUT_STAGE
#pragma unroll
  for (int i = 0; i < 4; ++i) {
    int orow = m0 + wm * 64 + i * 16 + quad * 4;
#pragma unroll
    for (int j = 0; j < 4; ++j) {
      int ncol = n0 + wn * 64 + j * 16 + l;
#pragma unroll
      for (int r = 0; r < 4; ++r) {
        size_t oi = ((size_t)b * CDIM + orow + r) * NSEQ + ncol;
        float v = acc[i][j][r] + ldx(bout, orow + r, f32) + ldx(x, oi, f32);
        stx(out, oi, f32, v);
      }
    }
  }
}

// ---------------- legacy kernel 5: out GEMM ----------------
__global__ __launch_bounds__(256) void out_gemm_kernel(
    const void* __restrict__ x, const void* __restrict__ g,
    const void* __restrict__ bln, const __hip_bfloat16* __restrict__ w3,
    const int* __restrict__ mode,
    const float* __restrict__ mean, const float* __restrict__ rstd,
    const void* __restrict__ bout, void* __restrict__ out) {
  const bool f32 = mode[0] != 0;
  const int b = blockIdx.z;
  const int m0 = blockIdx.y * 128;
  const int n0 = blockIdx.x * 128;
  __shared__ __align__(16) __hip_bfloat16 As[128 * 32];
  __shared__ __align__(16) __hip_bfloat16 Bs[128 * 40];
  const int tid = threadIdx.x;
  const int lane = tid & 63;
  const int wv = tid >> 6;
  const int wm = wv >> 1, wn = wv & 1;
  const int quad = lane >> 4, l = lane & 15;
  f32x4 acc[4][4] = {};
  const int nn = tid & 127;
  const int cb = tid >> 7;
  const float mn = mean[b * NSEQ + n0 + nn];
  const float rs = rstd[b * NSEQ + n0 + nn];
  const size_t xbase = (size_t)b * CDIM * NSEQ + n0 + nn;
  const __hip_bfloat16* wa = w3 + (size_t)b * CDIM * CDIM;
  for (int k0 = 0; k0 < CDIM; k0 += 32) {
#pragma unroll
    for (int r = 0; r < 2; ++r) {
      int idx = (r * 256 + tid) * 8;
      int row = idx >> 5, col = idx & 31;
      *(int4*)&As[idx] = *(const int4*)&wa[(size_t)(m0 + row) * CDIM + k0 + col];
    }
#pragma unroll
    for (int r = 0; r < 16; ++r) {
      int c = r * 2 + cb;
      float xv = ldx(x, xbase + (size_t)(k0 + c) * NSEQ, f32);
      float xn = (xv - mn) * rs;
      xn = xn * ldx(g, k0 + c, f32) + ldx(bln, k0 + c, f32);
      Bs[nn * 40 + c] = __float2bfloat16(xn);
    }
    __syncthreads();
    bf16x8 af[4], bfr[4];
#pragma unroll
    for (int i = 0; i < 4; ++i)
      af[i] = *(const bf16x8*)&As[(wm * 64 + i * 16 + l) * 32 + quad * 8];
#pragma unroll
    for (int j = 0; j < 4; ++j)
      bfr[j] = *(const bf16x8*)&Bs[(wn * 64 + j * 16 + l) * 40 + quad * 8];
#pragma unroll
    for (int i = 0; i < 4; ++i)
#pragma unroll
      for (int j = 0; j < 4; ++j)
        acc[i][j] = __builtin_amdgcn_mfma_f32_16x16x32_bf16(af[i], bfr[j], acc[i][j], 0, 0, 0);
    __syncthreads();
  }
#pragma unroll
  for (int i = 0; i < 4; ++i) {
    int orow = m0 + wm * 64 + i * 16 + quad * 4;
#pragma unroll
    for (int j = 0; j < 4; ++j) {
      int ncol = n0 + wn * 64 + j * 16 + l;
#pragma unroll
      for (int r = 0; r < 4; ++r) {
        size_t oi = ((size_t)b * CDIM + orow + r) * NSEQ + ncol;
        float v = acc[i][j][r] + ldx(bout, orow + r, f32) + ldx(x, oi, f32);
        stx(out, oi, f32, v);
      }
    }
  }
}

extern "C" void kernel_launch(void* const* d_in, const int* in_sizes, int n_in,
                              void* d_out, int out_size, void* d_ws, size_t ws_size,
                              hipStream_t stream) {
  (void)in_sizes; (void)n_in; (void)out_size;
  const void* x    = d_in[0];
  const void* g    = d_in[1];
  const void* bln  = d_in[2];
  const void* wqkv = d_in[3];
  const void* wout = d_in[4];
  const void* bout = d_in[5];

  float* mean   = (float*)d_ws;                    // 8*8192
  float* rstd   = mean + BATCH * NSEQ;             // 8*8192
  float* ctxb   = rstd + BATCH * NSEQ;             // 65536
  float* sumexp = ctxb + BATCH * HEADS * DH * DH;  // 2048
  int*   mode   = (int*)(sumexp + BATCH * HEADS * DH);
  __hip_bfloat16* w2  = (__hip_bfloat16*)(mode + 64);            // 8*512*256
  __hip_bfloat16* w3  = w2 + (size_t)BATCH * CDIM * HID;         // 8*512*512
  __hip_bfloat16* wb  = w3 + (size_t)BATCH * CDIM * CDIM;        // 768*512
  __hip_bfloat16* xnt = wb + (size_t)O3 * CDIM;                  // 8*8192*512
  const size_t need = (size_t)((const char*)(xnt + (size_t)BATCH * NSEQ * CDIM) - (const char*)d_ws);

  hipMemsetAsync(ctxb, 0, (BATCH * HEADS * DH * DH + BATCH * HEADS * DH) * sizeof(float), stream);
  detect_kernel<<<1, 256, 0, stream>>>(x, mode);

  if (ws_size >= need) {
    ln_stats4_kernel<<<dim3(NSEQ / 128, BATCH), 256, 0, stream>>>(x, mode, mean, rstd);
    wconv_kernel<<<dim3((O3 * CDIM) / 2048), 256, 0, stream>>>(wqkv, mode, wb);
    xnormt_kernel<<<dim3(NSEQ / 128, CDIM / 128, BATCH), 256, 0, stream>>>(
        x, g, bln, mode, mean, rstd, xnt);
    kv_gemm6_kernel<<<dim3(NSEQ / 256, HEADS / 2, BATCH), 512, 0, stream>>>(
        wb, xnt, ctxb, sumexp);
    w2_build_kernel<<<dim3(CDIM, BATCH), 256, 0, stream>>>(wout, mode, ctxb, sumexp, w2);
    w3_gemm2_kernel<<<dim3(CDIM / 128, CDIM / 128, BATCH), 256, 0, stream>>>(w2, wb, w3);
    out_gemm6_kernel<<<dim3(NSEQ / 256, CDIM / 128, BATCH), 512, 0, stream>>>(
        x, w3, xnt, mode, bout, d_out);
  } else {
    ln_stats_kernel<<<dim3(NSEQ / 64, BATCH), 256, 0, stream>>>(x, mode, mean, rstd);
    kvctx_kernel<<<dim3(NSEQ / 128, HEADS / 2, BATCH), 256, 0, stream>>>(
        x, g, bln, wqkv, mode, mean, rstd, ctxb, sumexp);
    w2_build_kernel<<<dim3(CDIM, BATCH), 256, 0, stream>>>(wout, mode, ctxb, sumexp, w2);
    w3_gemm_kernel<<<dim3(CDIM / 128, CDIM / 128, BATCH), 256, 0, stream>>>(w2, wqkv, mode, w3);
    out_gemm_kernel<<<dim3(NSEQ / 128, CDIM / 128, BATCH), 256, 0, stream>>>(
        x, g, bln, w3, mode, mean, rstd, bout, d_out);
  }
}